// Round 2
// baseline (1316.845 us; speedup 1.0000x reference)
//
#include <hip/hip_runtime.h>
#include <hip/hip_bf16.h>
#include <math.h>

// Problem constants
//  B=2, S=2048, H=768, NH=12, D=64, R=256, MAX_REL=128
//  M = B*S = 4096 rows for QKV GEMM; BH = B*NH = 24

#define LDS_ATOMIC_ADD(p, v) __hip_atomic_fetch_add((p), (v), __ATOMIC_RELAXED, __HIP_MEMORY_SCOPE_WORKGROUP)

// ---------------- Kernel 1: fused QKV projection ----------------
// hs [4096,768] @ W [768,768] + bias -> out in [B][NH][S][D] layout.
// grid (36, 64): x = weight(3) x n-block(12), y = m-block; 256 threads.
__global__ __launch_bounds__(256) void qkv_kernel(
    const float* __restrict__ hs,
    const float* __restrict__ Wq, const float* __restrict__ bq,
    const float* __restrict__ Wk, const float* __restrict__ bk,
    const float* __restrict__ Wv, const float* __restrict__ bv,
    float* __restrict__ qo, float* __restrict__ ko, float* __restrict__ vo) {
  __shared__ float As[16][68];
  __shared__ float Bs[16][68];
  const int t  = threadIdx.x;
  const int tx = t & 15, ty = t >> 4;
  const int nb = blockIdx.x;              // 0..35
  const int m0 = blockIdx.y * 64;
  const int w  = nb / 12;
  const int n0 = (nb % 12) * 64;
  const float* W    = (w == 0) ? Wq : (w == 1) ? Wk : Wv;
  const float* bias = (w == 0) ? bq : (w == 1) ? bk : bv;
  float* out        = (w == 0) ? qo : (w == 1) ? ko : vo;

  const int ak  = t & 15, am  = t >> 4;   // A tile: k-col, m-row base
  const int bn  = t & 63, bk0 = t >> 6;   // B tile: n-col, k-row base
  float c[4][4] = {};

  for (int k0 = 0; k0 < 768; k0 += 16) {
    #pragma unroll
    for (int r = 0; r < 4; ++r)
      As[ak][am + 16*r] = hs[(size_t)(m0 + am + 16*r)*768 + (k0 + ak)];
    #pragma unroll
    for (int r = 0; r < 4; ++r)
      Bs[bk0 + 4*r][bn] = W[(size_t)(k0 + bk0 + 4*r)*768 + (n0 + bn)];
    __syncthreads();
    #pragma unroll
    for (int k = 0; k < 16; ++k) {
      const float4 av  = *(const float4*)&As[k][ty*4];
      const float4 bv4 = *(const float4*)&Bs[k][tx*4];
      c[0][0] += av.x*bv4.x; c[0][1] += av.x*bv4.y; c[0][2] += av.x*bv4.z; c[0][3] += av.x*bv4.w;
      c[1][0] += av.y*bv4.x; c[1][1] += av.y*bv4.y; c[1][2] += av.y*bv4.z; c[1][3] += av.y*bv4.w;
      c[2][0] += av.z*bv4.x; c[2][1] += av.z*bv4.y; c[2][2] += av.z*bv4.z; c[2][3] += av.z*bv4.w;
      c[3][0] += av.w*bv4.x; c[3][1] += av.w*bv4.y; c[3][2] += av.w*bv4.z; c[3][3] += av.w*bv4.w;
    }
    __syncthreads();
  }

  const int h  = n0 >> 6;     // n0 is a multiple of 64 -> single head per block
  const int d0 = tx * 4;
  #pragma unroll
  for (int mm = 0; mm < 4; ++mm) {
    const int m = m0 + ty*4 + mm;
    const int b = m >> 11, s = m & 2047;
    float4 val;
    val.x = c[mm][0] + bias[n0 + d0 + 0];
    val.y = c[mm][1] + bias[n0 + d0 + 1];
    val.z = c[mm][2] + bias[n0 + d0 + 2];
    val.w = c[mm][3] + bias[n0 + d0 + 3];
    *(float4*)&out[(((size_t)b*12 + h)*2048 + s)*64 + d0] = val;
  }
}

// ---------------- Kernel 2: rel_scores = q @ rke^T * scale ----------------
// q flat [49152][64]; rke [256][64]; rs [49152][256].
// grid (768, 4): 64x64 tile, K=64 (single pass); 256 threads.
__global__ __launch_bounds__(256) void rel_scores_kernel(
    const float* __restrict__ q, const float* __restrict__ rke,
    float* __restrict__ rs) {
  __shared__ float As[64][68];
  __shared__ float Bs[64][68];
  const int t  = threadIdx.x;
  const int tx = t & 15, ty = t >> 4;
  const int m0 = blockIdx.x * 64;
  const int n0 = blockIdx.y * 64;

  #pragma unroll
  for (int e = 0; e < 16; ++e) {
    const int f = e*256 + t;
    const int row = f >> 6, col = f & 63;
    As[col][row] = q  [(size_t)(m0 + row)*64 + col];
    Bs[col][row] = rke[(size_t)(n0 + row)*64 + col];
  }
  __syncthreads();

  float c[4][4] = {};
  #pragma unroll
  for (int k = 0; k < 64; ++k) {
    const float4 av = *(const float4*)&As[k][ty*4];
    const float4 bv = *(const float4*)&Bs[k][tx*4];
    c[0][0] += av.x*bv.x; c[0][1] += av.x*bv.y; c[0][2] += av.x*bv.z; c[0][3] += av.x*bv.w;
    c[1][0] += av.y*bv.x; c[1][1] += av.y*bv.y; c[1][2] += av.y*bv.z; c[1][3] += av.y*bv.w;
    c[2][0] += av.z*bv.x; c[2][1] += av.z*bv.y; c[2][2] += av.z*bv.z; c[2][3] += av.z*bv.w;
    c[3][0] += av.w*bv.x; c[3][1] += av.w*bv.y; c[3][2] += av.w*bv.z; c[3][3] += av.w*bv.w;
  }

  #pragma unroll
  for (int mm = 0; mm < 4; ++mm) {
    float4 val;
    val.x = c[mm][0] * 0.125f;
    val.y = c[mm][1] * 0.125f;
    val.z = c[mm][2] * 0.125f;
    val.w = c[mm][3] * 0.125f;
    *(float4*)&rs[(size_t)(m0 + ty*4 + mm)*256 + n0 + tx*4] = val;
  }
}

// ---------------- Kernel 3: fused attention ----------------
// Per block: one (b,h), 32 i-rows; sweep all 2048 j in 32-tiles.
// Fixed-offset softmax (scores provably bounded ~[-4,4]); rel_probs
// accumulated unnormalized in LDS; saturated-bucket tiles (|j-i|>128 for the
// whole tile, ~54 of 64 tiles) take a register fast path with no atomics and
// no rel-score gather. grid (64, 24); 256 threads; j columns tx / tx+16.
__global__ __launch_bounds__(256) void attn_kernel(
    const float* __restrict__ q, const float* __restrict__ kmat,
    const float* __restrict__ vmat, const float* __restrict__ rs,
    const float* __restrict__ rve, const float* __restrict__ mask,
    float* __restrict__ out) {
  __shared__ float q_s[32][68];
  __shared__ float k_s[32][68];
  __shared__ float v_s[32][68];
  __shared__ float p_s[32][36];
  __shared__ float rp_s[32][256];
  __shared__ float l_s[32];

  const int t  = threadIdx.x;
  const int tx = t & 15, ty = t >> 4;
  const int bh = blockIdx.y;
  const int b  = bh / 12, h = bh % 12;
  const int i0 = blockIdx.x * 32;
  const int iA = 2*ty, iB = 2*ty + 1;
  const int jA = tx, jB = tx + 16;

  const float* qb  = q    + ((size_t)bh*2048 + i0)*64;
  const float* kb  = kmat + (size_t)bh*2048*64;
  const float* vb  = vmat + (size_t)bh*2048*64;
  const float* rsb = rs   + ((size_t)bh*2048 + i0)*256;
  const float* mb  = mask + (size_t)b*2048;

  for (int e = t; e < 32*256; e += 256) ((float*)rp_s)[e] = 0.0f;
  if (t < 32) l_s[t] = 0.0f;
  #pragma unroll
  for (int e = 0; e < 8; ++e) {
    const int f = e*256 + t;
    q_s[f >> 6][f & 63] = qb[(size_t)(f >> 6)*64 + (f & 63)];
  }
  __syncthreads();

  // row-constant rel scores for the saturated buckets
  const float rs_loA = rsb[iA*256 + 0],   rs_loB = rsb[iB*256 + 0];
  const float rs_hiA = rsb[iA*256 + 255], rs_hiB = rsb[iB*256 + 255];
  float rp_loA = 0.f, rp_loB = 0.f, rp_hiA = 0.f, rp_hiB = 0.f;

  float4 ctx0 = {0,0,0,0}, ctx1 = {0,0,0,0};
  float lsum0 = 0.0f, lsum1 = 0.0f;

  for (int j0 = 0; j0 < 2048; j0 += 32) {
    #pragma unroll
    for (int e = 0; e < 8; ++e) {
      const int f = e*256 + t;
      const int jr = f >> 6, d = f & 63;
      k_s[jr][d] = kb[(size_t)(j0 + jr)*64 + d];
      v_s[jr][d] = vb[(size_t)(j0 + jr)*64 + d];
    }
    __syncthreads();

    // --- QK^T 2x2 micro-tile (j = tx, tx+16: 2-way LDS banks, free) ---
    float s00 = 0.f, s01 = 0.f, s10 = 0.f, s11 = 0.f;
    #pragma unroll
    for (int kk = 0; kk < 64; kk += 4) {
      const float4 qa  = *(const float4*)&q_s[iA][kk];
      const float4 qbv = *(const float4*)&q_s[iB][kk];
      const float4 ka  = *(const float4*)&k_s[jA][kk];
      const float4 kbv = *(const float4*)&k_s[jB][kk];
      s00 += qa.x*ka.x  + qa.y*ka.y  + qa.z*ka.z  + qa.w*ka.w;
      s01 += qa.x*kbv.x + qa.y*kbv.y + qa.z*kbv.z + qa.w*kbv.w;
      s10 += qbv.x*ka.x  + qbv.y*ka.y  + qbv.z*ka.z  + qbv.w*ka.w;
      s11 += qbv.x*kbv.x + qbv.y*kbv.y + qbv.z*kbv.z + qbv.w*kbv.w;
    }

    const float mA = (1.0f - mb[j0 + jA]) * -10000.0f;
    const float mB = (1.0f - mb[j0 + jB]) * -10000.0f;

    if (j0 <= i0 - 160) {            // whole tile saturates to bucket 0
      const float p00 = __expf(s00*0.125f + rs_loA + mA - 8.0f);
      const float p01 = __expf(s01*0.125f + rs_loA + mB - 8.0f);
      const float p10 = __expf(s10*0.125f + rs_loB + mA - 8.0f);
      const float p11 = __expf(s11*0.125f + rs_loB + mB - 8.0f);
      p_s[iA][jA] = p00; p_s[iA][jB] = p01;
      p_s[iB][jA] = p10; p_s[iB][jB] = p11;
      rp_loA += p00 + p01; rp_loB += p10 + p11;
      lsum0  += p00 + p01; lsum1  += p10 + p11;
    } else if (j0 >= i0 + 160) {     // whole tile saturates to bucket 255
      const float p00 = __expf(s00*0.125f + rs_hiA + mA - 8.0f);
      const float p01 = __expf(s01*0.125f + rs_hiA + mB - 8.0f);
      const float p10 = __expf(s10*0.125f + rs_hiB + mA - 8.0f);
      const float p11 = __expf(s11*0.125f + rs_hiB + mB - 8.0f);
      p_s[iA][jA] = p00; p_s[iA][jB] = p01;
      p_s[iB][jA] = p10; p_s[iB][jB] = p11;
      rp_hiA += p00 + p01; rp_hiB += p10 + p11;
      lsum0  += p00 + p01; lsum1  += p10 + p11;
    } else {                         // band: per-element bucket + LDS atomic
      const float sv[2][2] = {{s00, s01}, {s10, s11}};
      #pragma unroll
      for (int a = 0; a < 2; ++a) {
        const int il = 2*ty + a;
        const int gi = i0 + il;
        #pragma unroll
        for (int cc = 0; cc < 2; ++cc) {
          const int jl = cc ? jB : jA;
          const int gj = j0 + jl;
          const int rel = gj - gi;
          const int bucket = (rel < -128 ? -128 : (rel > 127 ? 127 : rel)) + 128;
          const float mbias = cc ? mB : mA;
          const float s = sv[a][cc]*0.125f + rsb[il*256 + bucket] + mbias;
          const float p = __expf(s - 8.0f);
          p_s[il][jl] = p;
          LDS_ATOMIC_ADD(&rp_s[il][bucket], p);
          if (a == 0) lsum0 += p; else lsum1 += p;
        }
      }
    }
    __syncthreads();

    // --- PV accumulate (rows iA,iB x dims tx*4..tx*4+3) ---
    #pragma unroll
    for (int jj = 0; jj < 32; jj += 4) {
      const float4 pa = *(const float4*)&p_s[iA][jj];
      const float4 pb = *(const float4*)&p_s[iB][jj];
      const float4 v0 = *(const float4*)&v_s[jj+0][tx*4];
      const float4 v1 = *(const float4*)&v_s[jj+1][tx*4];
      const float4 v2 = *(const float4*)&v_s[jj+2][tx*4];
      const float4 v3 = *(const float4*)&v_s[jj+3][tx*4];
      ctx0.x += pa.x*v0.x + pa.y*v1.x + pa.z*v2.x + pa.w*v3.x;
      ctx0.y += pa.x*v0.y + pa.y*v1.y + pa.z*v2.y + pa.w*v3.y;
      ctx0.z += pa.x*v0.z + pa.y*v1.z + pa.z*v2.z + pa.w*v3.z;
      ctx0.w += pa.x*v0.w + pa.y*v1.w + pa.z*v2.w + pa.w*v3.w;
      ctx1.x += pb.x*v0.x + pb.y*v1.x + pb.z*v2.x + pb.w*v3.x;
      ctx1.y += pb.x*v0.y + pb.y*v1.y + pb.z*v2.y + pb.w*v3.y;
      ctx1.z += pb.x*v0.z + pb.y*v1.z + pb.z*v2.z + pb.w*v3.z;
      ctx1.w += pb.x*v0.w + pb.y*v1.w + pb.z*v2.w + pb.w*v3.w;
    }
    __syncthreads();
  }

  // fold register-accumulated saturated buckets + row sums into LDS
  LDS_ATOMIC_ADD(&rp_s[iA][0],   rp_loA);
  LDS_ATOMIC_ADD(&rp_s[iB][0],   rp_loB);
  LDS_ATOMIC_ADD(&rp_s[iA][255], rp_hiA);
  LDS_ATOMIC_ADD(&rp_s[iB][255], rp_hiB);
  LDS_ATOMIC_ADD(&l_s[iA], lsum0);
  LDS_ATOMIC_ADD(&l_s[iB], lsum1);
  __syncthreads();

  // --- epilogue: rel_probs @ rve, normalize, write out ---
  float4 r0 = {0,0,0,0}, r1 = {0,0,0,0};
  #pragma unroll 4
  for (int r4 = 0; r4 < 256; r4 += 4) {
    const float4 ra = *(const float4*)&rp_s[iA][r4];
    const float4 rb = *(const float4*)&rp_s[iB][r4];
    const float4 e0 = *(const float4*)&rve[(size_t)(r4+0)*64 + tx*4];
    const float4 e1 = *(const float4*)&rve[(size_t)(r4+1)*64 + tx*4];
    const float4 e2 = *(const float4*)&rve[(size_t)(r4+2)*64 + tx*4];
    const float4 e3 = *(const float4*)&rve[(size_t)(r4+3)*64 + tx*4];
    r0.x += ra.x*e0.x + ra.y*e1.x + ra.z*e2.x + ra.w*e3.x;
    r0.y += ra.x*e0.y + ra.y*e1.y + ra.z*e2.y + ra.w*e3.y;
    r0.z += ra.x*e0.z + ra.y*e1.z + ra.z*e2.z + ra.w*e3.z;
    r0.w += ra.x*e0.w + ra.y*e1.w + ra.z*e2.w + ra.w*e3.w;
    r1.x += rb.x*e0.x + rb.y*e1.x + rb.z*e2.x + rb.w*e3.x;
    r1.y += rb.x*e0.y + rb.y*e1.y + rb.z*e2.y + rb.w*e3.y;
    r1.z += rb.x*e0.z + rb.y*e1.z + rb.z*e2.z + rb.w*e3.z;
    r1.w += rb.x*e0.w + rb.y*e1.w + rb.z*e2.w + rb.w*e3.w;
  }
  const float inv0 = 1.0f / l_s[iA];
  const float inv1 = 1.0f / l_s[iB];
  float4 o0, o1;
  o0.x = (ctx0.x + r0.x)*inv0; o0.y = (ctx0.y + r0.y)*inv0;
  o0.z = (ctx0.z + r0.z)*inv0; o0.w = (ctx0.w + r0.w)*inv0;
  o1.x = (ctx1.x + r1.x)*inv1; o1.y = (ctx1.y + r1.y)*inv1;
  o1.z = (ctx1.z + r1.z)*inv1; o1.w = (ctx1.w + r1.w)*inv1;
  *(float4*)&out[((size_t)(b*2048 + i0 + iA))*768 + h*64 + tx*4] = o0;
  *(float4*)&out[((size_t)(b*2048 + i0 + iB))*768 + h*64 + tx*4] = o1;
}

// ---------------- launcher ----------------
extern "C" void kernel_launch(void* const* d_in, const int* in_sizes, int n_in,
                              void* d_out, int out_size, void* d_ws, size_t ws_size,
                              hipStream_t stream) {
  const float* hs   = (const float*)d_in[0];
  const float* mask = (const float*)d_in[1];
  const float* Wq   = (const float*)d_in[2];
  const float* bq   = (const float*)d_in[3];
  const float* Wk   = (const float*)d_in[4];
  const float* bk   = (const float*)d_in[5];
  const float* Wv   = (const float*)d_in[6];
  const float* bv   = (const float*)d_in[7];
  const float* rke  = (const float*)d_in[8];
  const float* rve  = (const float*)d_in[9];
  // d_in[10] = indices, recomputed analytically on device.

  // Workspace layout (floats): q,k,v [24][2048][64] each; rs [49152][256].
  const size_t need_bytes = (size_t)(3*3145728 + 12582912) * 4;  // 88,080,384
  if (ws_size < need_bytes) return;  // safe-fail: never write OOB scratch

  float* ws = (float*)d_ws;
  float* q  = ws;                   // 3,145,728 f
  float* k  = ws + 3145728;
  float* v  = ws + 6291456;
  float* rs = ws + 9437184;         // 12,582,912 f
  float* out = (float*)d_out;

  qkv_kernel<<<dim3(36, 64), dim3(256), 0, stream>>>(
      hs, Wq, bq, Wk, bk, Wv, bv, q, k, v);
  rel_scores_kernel<<<dim3(768, 4), dim3(256), 0, stream>>>(q, rke, rs);
  attn_kernel<<<dim3(64, 24), dim3(256), 0, stream>>>(
      q, k, v, rs, rve, mask, out);
}

// Round 3
// 510.083 us; speedup vs baseline: 2.5816x; 2.5816x over previous
//
#include <hip/hip_runtime.h>
#include <hip/hip_bf16.h>
#include <math.h>

// Problem constants: B=2, S=2048, H=768, NH=12, D=64, R=256, MAX_REL=128
// BH = 24; QKV GEMM rows M = 4096.

#define LDS_ATOMIC_ADD(p, v) __hip_atomic_fetch_add((p), (v), __ATOMIC_RELAXED, __HIP_MEMORY_SCOPE_WORKGROUP)

typedef short short8v __attribute__((ext_vector_type(8)));
typedef short short4v __attribute__((ext_vector_type(4)));
typedef float f32x4 __attribute__((ext_vector_type(4)));

#define MFMA16x16x32(a, b, c) __builtin_amdgcn_mfma_f32_16x16x32_bf16((a), (b), (c), 0, 0, 0)

// float -> bf16 bits, round-to-nearest-even (values are finite here)
__device__ inline short f2bf(float f) {
  unsigned u = __float_as_uint(f);
  unsigned r = (u + 0x7FFFu + ((u >> 16) & 1u)) >> 16;
  return (short)r;
}

// ---------------- Kernel 1: fused QKV projection ----------------
// hs [4096,768] @ W [768,768] + bias.
// w==0: writes fp32 q [bh][s][64] (for rel_scores) + bf16 q same layout.
// w==1: writes bf16 k [bh][s][64].
// w==2: writes bf16 v TRANSPOSED [bh][d][s]  (PV B-operand wants V^T).
__global__ __launch_bounds__(256) void qkv_kernel(
    const float* __restrict__ hs,
    const float* __restrict__ Wq, const float* __restrict__ bq,
    const float* __restrict__ Wk, const float* __restrict__ bk,
    const float* __restrict__ Wv, const float* __restrict__ bv,
    float* __restrict__ qo, short* __restrict__ qbf,
    short* __restrict__ kbf, short* __restrict__ vtbf) {
  __shared__ float As[16][68];
  __shared__ float Bs[16][68];
  const int t  = threadIdx.x;
  const int tx = t & 15, ty = t >> 4;
  const int nb = blockIdx.x;              // 0..35
  const int m0 = blockIdx.y * 64;
  const int w  = nb / 12;
  const int n0 = (nb % 12) * 64;
  const float* W    = (w == 0) ? Wq : (w == 1) ? Wk : Wv;
  const float* bias = (w == 0) ? bq : (w == 1) ? bk : bv;

  const int ak  = t & 15, am  = t >> 4;
  const int bn  = t & 63, bk0 = t >> 6;
  float c[4][4] = {};

  for (int k0 = 0; k0 < 768; k0 += 16) {
    #pragma unroll
    for (int r = 0; r < 4; ++r)
      As[ak][am + 16*r] = hs[(size_t)(m0 + am + 16*r)*768 + (k0 + ak)];
    #pragma unroll
    for (int r = 0; r < 4; ++r)
      Bs[bk0 + 4*r][bn] = W[(size_t)(k0 + bk0 + 4*r)*768 + (n0 + bn)];
    __syncthreads();
    #pragma unroll
    for (int k = 0; k < 16; ++k) {
      const float4 av  = *(const float4*)&As[k][ty*4];
      const float4 bv4 = *(const float4*)&Bs[k][tx*4];
      c[0][0] += av.x*bv4.x; c[0][1] += av.x*bv4.y; c[0][2] += av.x*bv4.z; c[0][3] += av.x*bv4.w;
      c[1][0] += av.y*bv4.x; c[1][1] += av.y*bv4.y; c[1][2] += av.y*bv4.z; c[1][3] += av.y*bv4.w;
      c[2][0] += av.z*bv4.x; c[2][1] += av.z*bv4.y; c[2][2] += av.z*bv4.z; c[2][3] += av.z*bv4.w;
      c[3][0] += av.w*bv4.x; c[3][1] += av.w*bv4.y; c[3][2] += av.w*bv4.z; c[3][3] += av.w*bv4.w;
    }
    __syncthreads();
  }

  const int h  = n0 >> 6;
  const int d0 = tx * 4;
  #pragma unroll
  for (int mm = 0; mm < 4; ++mm) {
    const int m = m0 + ty*4 + mm;
    const int b = m >> 11, s = m & 2047;
    float v0 = c[mm][0] + bias[n0 + d0 + 0];
    float v1 = c[mm][1] + bias[n0 + d0 + 1];
    float v2 = c[mm][2] + bias[n0 + d0 + 2];
    float v3 = c[mm][3] + bias[n0 + d0 + 3];
    const size_t bhrow = ((size_t)b*12 + h)*2048 + s;
    if (w == 0) {
      float4 val; val.x = v0; val.y = v1; val.z = v2; val.w = v3;
      *(float4*)&qo[bhrow*64 + d0] = val;
      short4v sv; sv[0] = f2bf(v0); sv[1] = f2bf(v1); sv[2] = f2bf(v2); sv[3] = f2bf(v3);
      *(short4v*)&qbf[bhrow*64 + d0] = sv;
    } else if (w == 1) {
      short4v sv; sv[0] = f2bf(v0); sv[1] = f2bf(v1); sv[2] = f2bf(v2); sv[3] = f2bf(v3);
      *(short4v*)&kbf[bhrow*64 + d0] = sv;
    } else {
      const size_t base = ((size_t)b*12 + h)*64;
      vtbf[(base + d0 + 0)*2048 + s] = f2bf(v0);
      vtbf[(base + d0 + 1)*2048 + s] = f2bf(v1);
      vtbf[(base + d0 + 2)*2048 + s] = f2bf(v2);
      vtbf[(base + d0 + 3)*2048 + s] = f2bf(v3);
    }
  }
}

// ---------------- Kernel 2: rel_scores = q @ rke^T * scale (fp32) ----------------
__global__ __launch_bounds__(256) void rel_scores_kernel(
    const float* __restrict__ q, const float* __restrict__ rke,
    float* __restrict__ rs) {
  __shared__ float As[64][68];
  __shared__ float Bs[64][68];
  const int t  = threadIdx.x;
  const int tx = t & 15, ty = t >> 4;
  const int m0 = blockIdx.x * 64;
  const int n0 = blockIdx.y * 64;

  #pragma unroll
  for (int e = 0; e < 16; ++e) {
    const int f = e*256 + t;
    const int row = f >> 6, col = f & 63;
    As[col][row] = q  [(size_t)(m0 + row)*64 + col];
    Bs[col][row] = rke[(size_t)(n0 + row)*64 + col];
  }
  __syncthreads();

  float c[4][4] = {};
  #pragma unroll
  for (int k = 0; k < 64; ++k) {
    const float4 av = *(const float4*)&As[k][ty*4];
    const float4 bv = *(const float4*)&Bs[k][tx*4];
    c[0][0] += av.x*bv.x; c[0][1] += av.x*bv.y; c[0][2] += av.x*bv.z; c[0][3] += av.x*bv.w;
    c[1][0] += av.y*bv.x; c[1][1] += av.y*bv.y; c[1][2] += av.y*bv.z; c[1][3] += av.y*bv.w;
    c[2][0] += av.z*bv.x; c[2][1] += av.z*bv.y; c[2][2] += av.z*bv.z; c[2][3] += av.z*bv.w;
    c[3][0] += av.w*bv.x; c[3][1] += av.w*bv.y; c[3][2] += av.w*bv.z; c[3][3] += av.w*bv.w;
  }

  #pragma unroll
  for (int mm = 0; mm < 4; ++mm) {
    float4 val;
    val.x = c[mm][0] * 0.125f;
    val.y = c[mm][1] * 0.125f;
    val.z = c[mm][2] * 0.125f;
    val.w = c[mm][3] * 0.125f;
    *(float4*)&rs[(size_t)(m0 + ty*4 + mm)*256 + n0 + tx*4] = val;
  }
}

// ---------------- Kernel 2b: rvet = rve^T as bf16 [64][256] ----------------
__global__ __launch_bounds__(256) void rvet_kernel(
    const float* __restrict__ rve, short* __restrict__ rvet) {
  const int t = threadIdx.x;
  #pragma unroll 4
  for (int e = 0; e < 64; ++e) {
    const int idx = e*256 + t;          // 16384 = 256 x 64
    const int r = idx >> 6, d = idx & 63;
    rvet[d*256 + r] = f2bf(rve[idx]);
  }
}

// ---------------- Kernel 3: fused attention, MFMA bf16 ----------------
// Block: one (b,h), 32 i-rows; 4 waves = (i-half) x (j/d-half); j-tiles of 64.
// mfma_f32_16x16x32_bf16; C layout: row=(lane>>4)*4+reg, col=lane&15.
// LDS XOR swizzle: elem = row*64 + (col ^ ((row&7)<<3)) for all bf16 tiles.
// Fixed-offset softmax exp(s-8); rel_probs: saturated tiles -> registers,
// band tiles -> LDS f32 atomics; rel-value epilogue also MFMA (K=256).
__global__ __launch_bounds__(256) void attn_mfma_kernel(
    const short* __restrict__ qbf, const short* __restrict__ kbf,
    const short* __restrict__ vtbf, const float* __restrict__ rs,
    const short* __restrict__ rvet, const float* __restrict__ mask,
    float* __restrict__ out) {
  __shared__ __align__(16) char smem[73856];
  short* q_lds  = (short*)smem;                 // [32*64]   4096 B
  short* k_lds  = (short*)(smem + 4096);        // [2][64*64] 16384 B
  short* vt_lds = (short*)(smem + 20480);       // [2][64*64] 16384 B
  short* p_lds  = (short*)(smem + 36864);       // [32*64]   4096 B
  float* rp_f   = (float*)(smem + 40960);       // [32*256]  32768 B
  float* l_s    = (float*)(smem + 73728);       // [32]      128 B
  short* rp_bf  = (short*)(smem + 4096);        // alias k_lds, [32*256] bf16

  const int t    = threadIdx.x;
  const int lane = t & 63, wv = t >> 6;
  const int ih   = wv & 1, jh = wv >> 1;        // i-half; j-half (QK) = d-half (PV)
  const int lrow = lane & 15, g = lane >> 4;
  const int swz  = (lrow & 7) << 3;             // read-side frag swizzle

  const int bh = blockIdx.y, b = bh / 12, h = bh % 12;
  const int i0 = blockIdx.x * 32;

  const short* qb  = qbf  + ((size_t)bh*2048 + i0)*64;
  const short* kb  = kbf  + (size_t)bh*2048*64;
  const short* vtb = vtbf + (size_t)bh*64*2048;
  const float* rsb = rs   + ((size_t)bh*2048 + i0)*256;
  const float* mb  = mask + (size_t)b*2048;

  // zero rp / l
  {
    f32x4 z = {0.f, 0.f, 0.f, 0.f};
    #pragma unroll
    for (int e = 0; e < 8; ++e) *(f32x4*)&rp_f[(e*256 + t)*4] = z;
    if (t < 32) l_s[t] = 0.f;
  }
  // stage q (32 rows x 8 chunks = 256 chunks, 1/thread)
  {
    const int row = t >> 3, c = t & 7;
    *(short8v*)&q_lds[row*64 + ((c ^ (row & 7))*8)] =
        *(const short8v*)&qb[row*64 + c*8];
  }
  // stage k/vt tile 0 into buf 0 (512 chunks each, 2/thread)
  #pragma unroll
  for (int e = 0; e < 2; ++e) {
    const int id = t + 256*e, row = id >> 3, c = id & 7;
    *(short8v*)&k_lds[row*64 + ((c ^ (row & 7))*8)] =
        *(const short8v*)&kb[(size_t)row*64 + c*8];
    *(short8v*)&vt_lds[row*64 + ((c ^ (row & 7))*8)] =
        *(const short8v*)&vtb[(size_t)row*2048 + c*8];
  }
  __syncthreads();

  // hoisted Q A-fragments (loop-invariant)
  const short8v aq0 = *(const short8v*)&q_lds[(ih*16 + lrow)*64 + ((g*8) ^ swz)];
  const short8v aq1 = *(const short8v*)&q_lds[(ih*16 + lrow)*64 + ((32 + g*8) ^ swz)];

  // per-lane row constants (rows ih*16 + 4g + r)
  float rs_lo[4], rs_hi[4];
  #pragma unroll
  for (int r = 0; r < 4; ++r) {
    const int il = ih*16 + 4*g + r;
    rs_lo[r] = rsb[il*256 + 0];
    rs_hi[r] = rsb[il*256 + 255];
  }
  float ls_p[4]  = {0,0,0,0};
  float rpl_p[4] = {0,0,0,0};
  float rph_p[4] = {0,0,0,0};
  f32x4 ctx0 = {0,0,0,0}, ctx1 = {0,0,0,0};

  const int srow0 = t >> 3, sc = t & 7, srow1 = (t >> 3) + 32;

  for (int jt = 0; jt < 32; ++jt) {
    const int j0 = jt * 64;
    short* kl  = k_lds  + (jt & 1) * 4096;
    short* vl  = vt_lds + (jt & 1) * 4096;
    short* kln = k_lds  + ((jt & 1) ^ 1) * 4096;
    short* vln = vt_lds + ((jt & 1) ^ 1) * 4096;
    const bool have_next = (jt < 31);

    short8v stk0, stk1, stv0, stv1;
    if (have_next) {                 // issue next-tile global loads early
      const int j0n = j0 + 64;
      stk0 = *(const short8v*)&kb[(size_t)(j0n + srow0)*64 + sc*8];
      stk1 = *(const short8v*)&kb[(size_t)(j0n + srow1)*64 + sc*8];
      stv0 = *(const short8v*)&vtb[(size_t)srow0*2048 + j0n + sc*8];
      stv1 = *(const short8v*)&vtb[(size_t)srow1*2048 + j0n + sc*8];
    }

    // --- QK^T: 2 C-tiles (n=0,1), K=64 in 2 steps ---
    f32x4 c0 = {0,0,0,0}, c1 = {0,0,0,0};
    {
      const int jr0 = jh*32 + lrow, jr1 = jh*32 + 16 + lrow;
      const short8v b00 = *(const short8v*)&kl[jr0*64 + ((g*8) ^ swz)];
      const short8v b01 = *(const short8v*)&kl[jr0*64 + ((32 + g*8) ^ swz)];
      const short8v b10 = *(const short8v*)&kl[jr1*64 + ((g*8) ^ swz)];
      const short8v b11 = *(const short8v*)&kl[jr1*64 + ((32 + g*8) ^ swz)];
      c0 = MFMA16x16x32(aq0, b00, c0);
      c0 = MFMA16x16x32(aq1, b01, c0);
      c1 = MFMA16x16x32(aq0, b10, c1);
      c1 = MFMA16x16x32(aq1, b11, c1);
    }

    const float m0v = (1.0f - mb[j0 + jh*32 + lrow])      * -10000.0f;
    const float m1v = (1.0f - mb[j0 + jh*32 + 16 + lrow]) * -10000.0f;

    if (j0 <= i0 - 192) {            // whole tile -> bucket 0
      #pragma unroll
      for (int r = 0; r < 4; ++r) {
        const int il  = ih*16 + 4*g + r;
        const int wsw = ((4*g + r) & 7) << 3;
        const float p0 = __expf(c0[r]*0.125f + rs_lo[r] + m0v - 8.0f);
        const float p1 = __expf(c1[r]*0.125f + rs_lo[r] + m1v - 8.0f);
        p_lds[il*64 + ((jh*32 + lrow) ^ wsw)]      = f2bf(p0);
        p_lds[il*64 + ((jh*32 + 16 + lrow) ^ wsw)] = f2bf(p1);
        rpl_p[r] += p0 + p1; ls_p[r] += p0 + p1;
      }
    } else if (j0 >= i0 + 159) {     // whole tile -> bucket 255
      #pragma unroll
      for (int r = 0; r < 4; ++r) {
        const int il  = ih*16 + 4*g + r;
        const int wsw = ((4*g + r) & 7) << 3;
        const float p0 = __expf(c0[r]*0.125f + rs_hi[r] + m0v - 8.0f);
        const float p1 = __expf(c1[r]*0.125f + rs_hi[r] + m1v - 8.0f);
        p_lds[il*64 + ((jh*32 + lrow) ^ wsw)]      = f2bf(p0);
        p_lds[il*64 + ((jh*32 + 16 + lrow) ^ wsw)] = f2bf(p1);
        rph_p[r] += p0 + p1; ls_p[r] += p0 + p1;
      }
    } else {                         // band: per-element bucket
      #pragma unroll
      for (int r = 0; r < 4; ++r) {
        const int il  = ih*16 + 4*g + r;
        const int gi  = i0 + il;
        const int wsw = ((4*g + r) & 7) << 3;
        {
          const int jl = jh*32 + lrow, gj = j0 + jl;
          int rel = gj - gi; rel = rel < -128 ? -128 : (rel > 127 ? 127 : rel);
          const int bk = rel + 128;
          const float p = __expf(c0[r]*0.125f + rsb[il*256 + bk] + m0v - 8.0f);
          p_lds[il*64 + (jl ^ wsw)] = f2bf(p);
          LDS_ATOMIC_ADD(&rp_f[il*256 + bk], p);
          ls_p[r] += p;
        }
        {
          const int jl = jh*32 + 16 + lrow, gj = j0 + jl;
          int rel = gj - gi; rel = rel < -128 ? -128 : (rel > 127 ? 127 : rel);
          const int bk = rel + 128;
          const float p = __expf(c1[r]*0.125f + rsb[il*256 + bk] + m1v - 8.0f);
          p_lds[il*64 + (jl ^ wsw)] = f2bf(p);
          LDS_ATOMIC_ADD(&rp_f[il*256 + bk], p);
          ls_p[r] += p;
        }
      }
    }
    __syncthreads();

    // --- PV: ctx[i][d] += P[i][:] @ V[:, d]  (B = vt rows = d) ---
    {
      const int prow = ih*16 + lrow;
      const short8v pa0 = *(const short8v*)&p_lds[prow*64 + ((g*8) ^ swz)];
      const short8v pa1 = *(const short8v*)&p_lds[prow*64 + ((32 + g*8) ^ swz)];
      const int d0 = jh*32 + lrow, d1 = jh*32 + 16 + lrow;
      const short8v vb00 = *(const short8v*)&vl[d0*64 + ((g*8) ^ swz)];
      const short8v vb01 = *(const short8v*)&vl[d0*64 + ((32 + g*8) ^ swz)];
      const short8v vb10 = *(const short8v*)&vl[d1*64 + ((g*8) ^ swz)];
      const short8v vb11 = *(const short8v*)&vl[d1*64 + ((32 + g*8) ^ swz)];
      ctx0 = MFMA16x16x32(pa0, vb00, ctx0);
      ctx0 = MFMA16x16x32(pa1, vb01, ctx0);
      ctx1 = MFMA16x16x32(pa0, vb10, ctx1);
      ctx1 = MFMA16x16x32(pa1, vb11, ctx1);
    }
    if (have_next) {                 // write staged regs into the other buffer
      *(short8v*)&kln[srow0*64 + ((sc ^ (srow0 & 7))*8)] = stk0;
      *(short8v*)&kln[srow1*64 + ((sc ^ (srow1 & 7))*8)] = stk1;
      *(short8v*)&vln[srow0*64 + ((sc ^ (srow0 & 7))*8)] = stv0;
      *(short8v*)&vln[srow1*64 + ((sc ^ (srow1 & 7))*8)] = stv1;
    }
    __syncthreads();
  }

  // --- fold per-lane partials: reduce over the 16 lanes of each row-group ---
  #pragma unroll
  for (int r = 0; r < 4; ++r) {
    float a = ls_p[r], bl = rpl_p[r], bhv = rph_p[r];
    #pragma unroll
    for (int m = 1; m < 16; m <<= 1) {
      a   += __shfl_xor(a, m);
      bl  += __shfl_xor(bl, m);
      bhv += __shfl_xor(bhv, m);
    }
    if (lrow == 0) {
      const int il = ih*16 + 4*g + r;
      LDS_ATOMIC_ADD(&l_s[il], a);
      LDS_ATOMIC_ADD(&rp_f[il*256 + 0], bl);
      LDS_ATOMIC_ADD(&rp_f[il*256 + 255], bhv);
    }
  }
  __syncthreads();

  // --- convert rp (f32) -> rp_bf (A layout, aliases k_lds) ---
  #pragma unroll
  for (int e = 0; e < 4; ++e) {
    const int id = t + 256*e;            // 1024 chunks of 8
    const int row = id >> 5, c = id & 31;
    const float* src = &rp_f[row*256 + c*8];
    short8v v;
    #pragma unroll
    for (int i = 0; i < 8; ++i) v[i] = f2bf(src[i]);
    *(short8v*)&rp_bf[row*256 + ((c ^ (row & 7))*8)] = v;
  }
  __syncthreads();

  // --- rel-value epilogue: ctx += rp @ rve  (K=256, B from global rvet) ---
  {
    const int arow = ih*16 + lrow;
    const int d0 = jh*32 + lrow, d1 = jh*32 + 16 + lrow;
    #pragma unroll
    for (int ks = 0; ks < 8; ++ks) {
      const short8v a  = *(const short8v*)&rp_bf[arow*256 + (((ks*4 + g) ^ (lrow & 7))*8)];
      const short8v b0 = *(const short8v*)&rvet[d0*256 + ks*32 + g*8];
      const short8v b1 = *(const short8v*)&rvet[d1*256 + ks*32 + g*8];
      ctx0 = MFMA16x16x32(a, b0, ctx0);
      ctx1 = MFMA16x16x32(a, b1, ctx1);
    }
  }

  // --- normalize + store ---
  #pragma unroll
  for (int r = 0; r < 4; ++r) {
    const int il = ih*16 + 4*g + r;
    const float invl = 1.0f / l_s[il];
    const int gi = i0 + il;
    out[(size_t)(b*2048 + gi)*768 + h*64 + jh*32 + lrow]      = ctx0[r] * invl;
    out[(size_t)(b*2048 + gi)*768 + h*64 + jh*32 + 16 + lrow] = ctx1[r] * invl;
  }
}

// ---------------- launcher ----------------
extern "C" void kernel_launch(void* const* d_in, const int* in_sizes, int n_in,
                              void* d_out, int out_size, void* d_ws, size_t ws_size,
                              hipStream_t stream) {
  const float* hs   = (const float*)d_in[0];
  const float* mask = (const float*)d_in[1];
  const float* Wq   = (const float*)d_in[2];
  const float* bq   = (const float*)d_in[3];
  const float* Wk   = (const float*)d_in[4];
  const float* bk   = (const float*)d_in[5];
  const float* Wv   = (const float*)d_in[6];
  const float* bv   = (const float*)d_in[7];
  const float* rke  = (const float*)d_in[8];
  const float* rve  = (const float*)d_in[9];
  // d_in[10] = indices, recomputed analytically on device.

  // Workspace: q f32 [24*2048*64]; rs f32 [49152*256];
  //            bf16: qbf, kbf, vtbf [24*2048*64] each; rvet [64*256].
  const size_t need_bytes = (size_t)15728640*4 + (size_t)(9437184 + 16384)*2; // 81,821,696
  if (ws_size < need_bytes) return;

  float* ws   = (float*)d_ws;
  float* q    = ws;                       // 3,145,728 f32
  float* rsw  = ws + 3145728;             // 12,582,912 f32
  short* bfb  = (short*)(ws + 15728640);
  short* qbf  = bfb;                      // 3,145,728 bf16
  short* kbf  = bfb + 3145728;
  short* vtbf = bfb + 6291456;
  short* rvet = bfb + 9437184;            // 16,384 bf16
  float* out  = (float*)d_out;

  qkv_kernel<<<dim3(36, 64), dim3(256), 0, stream>>>(
      hs, Wq, bq, Wk, bk, Wv, bv, q, qbf, kbf, vtbf);
  rvet_kernel<<<dim3(1), dim3(256), 0, stream>>>(rve, rvet);
  rel_scores_kernel<<<dim3(768, 4), dim3(256), 0, stream>>>(q, rke, rsw);
  attn_mfma_kernel<<<dim3(64, 24), dim3(256), 0, stream>>>(
      qbf, kbf, vtbf, rsw, rvet, mask, out);
}

// Round 4
// 361.061 us; speedup vs baseline: 3.6472x; 1.4127x over previous
//
#include <hip/hip_runtime.h>
#include <hip/hip_bf16.h>
#include <math.h>

// Problem constants: B=2, S=2048, H=768, NH=12, D=64, R=256, MAX_REL=128
// BH = 24; QKV GEMM rows M = 4096.

#define LDS_ATOMIC_ADD(p, v) __hip_atomic_fetch_add((p), (v), __ATOMIC_RELAXED, __HIP_MEMORY_SCOPE_WORKGROUP)

typedef short short8v __attribute__((ext_vector_type(8)));
typedef short short4v __attribute__((ext_vector_type(4)));
typedef float f32x4 __attribute__((ext_vector_type(4)));

#define MFMA16x16x32(a, b, c) __builtin_amdgcn_mfma_f32_16x16x32_bf16((a), (b), (c), 0, 0, 0)

// float -> bf16 bits, round-to-nearest-even (values are finite here)
__device__ inline short f2bf(float f) {
  unsigned u = __float_as_uint(f);
  unsigned r = (u + 0x7FFFu + ((u >> 16) & 1u)) >> 16;
  return (short)r;
}
__device__ inline float bf2f(short b) {
  return __uint_as_float(((unsigned)(unsigned short)b) << 16);
}

// ---------------- Prep A: hs -> (hi, lo) bf16 split ----------------
// 3,145,728 floats; 8 per thread; grid 1536 x 256.
__global__ __launch_bounds__(256) void prep_hs_kernel(
    const float* __restrict__ hs, short* __restrict__ hi, short* __restrict__ lo) {
  const size_t base = ((size_t)blockIdx.x * 256 + threadIdx.x) * 8;
  const float4 a = *(const float4*)&hs[base];
  const float4 b = *(const float4*)&hs[base + 4];
  float x[8] = {a.x, a.y, a.z, a.w, b.x, b.y, b.z, b.w};
  short8v h, l;
  #pragma unroll
  for (int i = 0; i < 8; ++i) {
    h[i] = f2bf(x[i]);
    l[i] = f2bf(x[i] - bf2f(h[i]));
  }
  *(short8v*)&hi[base] = h;
  *(short8v*)&lo[base] = l;
}

// ---------------- Prep B: W [768k][768n] -> WT bf16 [w][768n][768k] ----------------
// grid (12, 12, 3); 64x64 LDS transpose tiles.
__global__ __launch_bounds__(256) void prep_wt_kernel(
    const float* __restrict__ Wq, const float* __restrict__ Wk,
    const float* __restrict__ Wv, short* __restrict__ wt) {
  __shared__ float tile[64][65];
  const int t = threadIdx.x, tx = t & 15, ty = t >> 4;
  const int w = blockIdx.z;
  const float* W = (w == 0) ? Wq : (w == 1) ? Wk : Wv;
  const int k0 = blockIdx.x * 64, n0 = blockIdx.y * 64;
  #pragma unroll
  for (int rr = 0; rr < 4; ++rr) {
    const int kr = rr * 16 + ty;
    const float4 v = *(const float4*)&W[(size_t)(k0 + kr) * 768 + n0 + tx * 4];
    tile[kr][tx*4 + 0] = v.x; tile[kr][tx*4 + 1] = v.y;
    tile[kr][tx*4 + 2] = v.z; tile[kr][tx*4 + 3] = v.w;
  }
  __syncthreads();
  #pragma unroll
  for (int rr = 0; rr < 4; ++rr) {
    const int nr = rr * 16 + ty;
    short4v s;
    #pragma unroll
    for (int c = 0; c < 4; ++c) s[c] = f2bf(tile[tx*4 + c][nr]);
    *(short4v*)&wt[((size_t)w * 768 + n0 + nr) * 768 + k0 + tx * 4] = s;
  }
}

// ---------------- Prep C: rvet = rve^T bf16 [64][256]; rkeb = rke bf16 ----------------
__global__ __launch_bounds__(256) void rvet_kernel(
    const float* __restrict__ rve, const float* __restrict__ rke,
    short* __restrict__ rvet, short* __restrict__ rkeb) {
  const int t = threadIdx.x;
  #pragma unroll 4
  for (int e = 0; e < 64; ++e) {
    const int idx = e*256 + t;          // 16384 = 256 x 64
    const int r = idx >> 6, d = idx & 63;
    rvet[d*256 + r] = f2bf(rve[idx]);
    rkeb[idx]       = f2bf(rke[idx]);
  }
}

// ---------------- Kernel 1: QKV projection, MFMA bf16x2 ----------------
// C = (hs_hi + hs_lo) @ W_bf16 + bias.  A split hi/lo (2 MFMAs per pair)
// bounds the dtype error to W-quantization only (~0.2% rel on q/k/v).
// Tile 128m x 128n, BK=64, 4 waves (2x2), wave tile 64x64.
// LDS: 3 swizzled bf16 tiles [128][64] = 48 KB, single-buffered with
// register prefetch (issue next K-step loads before compute, write after).
// w==0 -> qbf [bh][s][64]; w==1 -> kbf; w==2 -> vtbf transposed [bh][d][s].
__global__ __launch_bounds__(256) void qkv_mfma_kernel(
    const short* __restrict__ hs_hi, const short* __restrict__ hs_lo,
    const short* __restrict__ wt,
    const float* __restrict__ bq, const float* __restrict__ bk,
    const float* __restrict__ bv,
    short* __restrict__ qbf, short* __restrict__ kbf, short* __restrict__ vtbf) {
  __shared__ short lds[3 * 8192];
  short* Ah = lds;                 // [128][64] swizzled
  short* Al = lds + 8192;
  short* Bt = lds + 16384;         // [128 n-rows][64 k]

  const int t = threadIdx.x, lane = t & 63, wv = t >> 6;
  const int wm = wv & 1, wn = wv >> 1;
  const int lrow = lane & 15, g = lane >> 4;
  const int m0 = blockIdx.x * 128, n0 = blockIdx.y * 128, w = blockIdx.z;
  const short* Bg = wt + (size_t)w * 768 * 768;
  const float* bias = (w == 0) ? bq : (w == 1) ? bk : bv;

  // staging geometry: 1024 chunks (8 bf16) per tile, 4 per thread
  int srow[4], sc[4];
  #pragma unroll
  for (int e = 0; e < 4; ++e) {
    const int id = t + 256*e;
    srow[e] = id >> 3; sc[e] = id & 7;
  }

  // prologue: stage K-step 0
  #pragma unroll
  for (int e = 0; e < 4; ++e) {
    const int row = srow[e], c = sc[e];
    const int dst = row*64 + ((c ^ (row & 7)) * 8);
    *(short8v*)&Ah[dst] = *(const short8v*)&hs_hi[(size_t)(m0 + row)*768 + c*8];
    *(short8v*)&Al[dst] = *(const short8v*)&hs_lo[(size_t)(m0 + row)*768 + c*8];
    *(short8v*)&Bt[dst] = *(const short8v*)&Bg[(size_t)(n0 + row)*768 + c*8];
  }
  __syncthreads();

  f32x4 acc[4][4] = {};

  for (int kt = 0; kt < 12; ++kt) {
    short8v pa[4], pl[4], pb[4];
    const bool have_next = (kt < 11);
    if (have_next) {
      const int k0n = (kt + 1) * 64;
      #pragma unroll
      for (int e = 0; e < 4; ++e) {
        const int row = srow[e], c = sc[e];
        pa[e] = *(const short8v*)&hs_hi[(size_t)(m0 + row)*768 + k0n + c*8];
        pl[e] = *(const short8v*)&hs_lo[(size_t)(m0 + row)*768 + k0n + c*8];
        pb[e] = *(const short8v*)&Bg   [(size_t)(n0 + row)*768 + k0n + c*8];
      }
    }

    #pragma unroll
    for (int kc = 0; kc < 2; ++kc) {
      short8v af[4], alf[4], bfv[4];
      #pragma unroll
      for (int fm = 0; fm < 4; ++fm) {
        const int row = wm*64 + fm*16 + lrow;
        const int off = row*64 + (((kc*4 + g) ^ (row & 7)) * 8);
        af[fm]  = *(const short8v*)&Ah[off];
        alf[fm] = *(const short8v*)&Al[off];
      }
      #pragma unroll
      for (int fn = 0; fn < 4; ++fn) {
        const int row = wn*64 + fn*16 + lrow;
        bfv[fn] = *(const short8v*)&Bt[row*64 + (((kc*4 + g) ^ (row & 7)) * 8)];
      }
      #pragma unroll
      for (int fm = 0; fm < 4; ++fm)
        #pragma unroll
        for (int fn = 0; fn < 4; ++fn) {
          acc[fm][fn] = MFMA16x16x32(af[fm],  bfv[fn], acc[fm][fn]);
          acc[fm][fn] = MFMA16x16x32(alf[fm], bfv[fn], acc[fm][fn]);
        }
    }
    __syncthreads();
    if (have_next) {
      #pragma unroll
      for (int e = 0; e < 4; ++e) {
        const int row = srow[e], c = sc[e];
        const int dst = row*64 + ((c ^ (row & 7)) * 8);
        *(short8v*)&Ah[dst] = pa[e];
        *(short8v*)&Al[dst] = pl[e];
        *(short8v*)&Bt[dst] = pb[e];
      }
    }
    __syncthreads();
  }

  // epilogue: bias + bf16 store into q/k/v layouts
  float bias_v[4];
  #pragma unroll
  for (int fn = 0; fn < 4; ++fn) bias_v[fn] = bias[n0 + wn*64 + fn*16 + lrow];

  #pragma unroll
  for (int fm = 0; fm < 4; ++fm) {
    #pragma unroll
    for (int r = 0; r < 4; ++r) {
      const int m = m0 + wm*64 + fm*16 + g*4 + r;
      const int b = m >> 11, s = m & 2047;
      #pragma unroll
      for (int fn = 0; fn < 4; ++fn) {
        const int n = n0 + wn*64 + fn*16 + lrow;
        const int h = n >> 6, d = n & 63;
        const size_t bh = (size_t)b*12 + h;
        const short sv = f2bf(acc[fm][fn][r] + bias_v[fn]);
        if (w == 0)      qbf [(bh*2048 + s)*64 + d] = sv;
        else if (w == 1) kbf [(bh*2048 + s)*64 + d] = sv;
        else             vtbf[(bh*64 + d)*2048 + s] = sv;
      }
    }
  }
}

// ---------------- Kernel 2: rel_scores = q @ rke^T * scale (MFMA bf16) ----------------
// A = qbf flat [49152][64]; B = rkeb [256][64]; C -> rs fp32 [49152][256].
// Tile 256m x 64n, K=64 single pass; 4 waves, each 64m x 64n.
__global__ __launch_bounds__(256) void rel_scores_mfma_kernel(
    const short* __restrict__ qbf, const short* __restrict__ rkeb,
    float* __restrict__ rs) {
  __shared__ short Atile[256 * 64];   // 32 KB swizzled
  __shared__ short Btile[64 * 64];    //  8 KB swizzled
  const int t = threadIdx.x, lane = t & 63, wv = t >> 6;
  const int lrow = lane & 15, g = lane >> 4;
  const int m0 = blockIdx.x * 256, n0 = blockIdx.y * 64;

  #pragma unroll
  for (int e = 0; e < 8; ++e) {
    const int id = t + 256*e, row = id >> 3, c = id & 7;
    *(short8v*)&Atile[row*64 + ((c ^ (row & 7)) * 8)] =
        *(const short8v*)&qbf[(size_t)(m0 + row)*64 + c*8];
  }
  #pragma unroll
  for (int e = 0; e < 2; ++e) {
    const int id = t + 256*e, row = id >> 3, c = id & 7;
    *(short8v*)&Btile[row*64 + ((c ^ (row & 7)) * 8)] =
        *(const short8v*)&rkeb[(size_t)(n0 + row)*64 + c*8];
  }
  __syncthreads();

  f32x4 acc[4][4] = {};
  #pragma unroll
  for (int kc = 0; kc < 2; ++kc) {
    short8v af[4], bfv[4];
    #pragma unroll
    for (int fm = 0; fm < 4; ++fm) {
      const int row = wv*64 + fm*16 + lrow;
      af[fm] = *(const short8v*)&Atile[row*64 + (((kc*4 + g) ^ (row & 7)) * 8)];
    }
    #pragma unroll
    for (int fn = 0; fn < 4; ++fn) {
      const int row = fn*16 + lrow;
      bfv[fn] = *(const short8v*)&Btile[row*64 + (((kc*4 + g) ^ (row & 7)) * 8)];
    }
    #pragma unroll
    for (int fm = 0; fm < 4; ++fm)
      #pragma unroll
      for (int fn = 0; fn < 4; ++fn)
        acc[fm][fn] = MFMA16x16x32(af[fm], bfv[fn], acc[fm][fn]);
  }

  #pragma unroll
  for (int fm = 0; fm < 4; ++fm)
    #pragma unroll
    for (int r = 0; r < 4; ++r) {
      const int m = m0 + wv*64 + fm*16 + g*4 + r;
      #pragma unroll
      for (int fn = 0; fn < 4; ++fn)
        rs[(size_t)m*256 + n0 + fn*16 + lrow] = acc[fm][fn][r] * 0.125f;
    }
}

// ---------------- Kernel 3: fused attention, MFMA bf16 (UNCHANGED) ----------------
__global__ __launch_bounds__(256) void attn_mfma_kernel(
    const short* __restrict__ qbf, const short* __restrict__ kbf,
    const short* __restrict__ vtbf, const float* __restrict__ rs,
    const short* __restrict__ rvet, const float* __restrict__ mask,
    float* __restrict__ out) {
  __shared__ __align__(16) char smem[73856];
  short* q_lds  = (short*)smem;                 // [32*64]   4096 B
  short* k_lds  = (short*)(smem + 4096);        // [2][64*64] 16384 B
  short* vt_lds = (short*)(smem + 20480);       // [2][64*64] 16384 B
  short* p_lds  = (short*)(smem + 36864);       // [32*64]   4096 B
  float* rp_f   = (float*)(smem + 40960);       // [32*256]  32768 B
  float* l_s    = (float*)(smem + 73728);       // [32]      128 B
  short* rp_bf  = (short*)(smem + 4096);        // alias k_lds, [32*256] bf16

  const int t    = threadIdx.x;
  const int lane = t & 63, wv = t >> 6;
  const int ih   = wv & 1, jh = wv >> 1;
  const int lrow = lane & 15, g = lane >> 4;
  const int swz  = (lrow & 7) << 3;

  const int bh = blockIdx.y, b = bh / 12, h = bh % 12;
  const int i0 = blockIdx.x * 32;

  const short* qb  = qbf  + ((size_t)bh*2048 + i0)*64;
  const short* kb  = kbf  + (size_t)bh*2048*64;
  const short* vtb = vtbf + (size_t)bh*64*2048;
  const float* rsb = rs   + ((size_t)bh*2048 + i0)*256;
  const float* mb  = mask + (size_t)b*2048;

  {
    f32x4 z = {0.f, 0.f, 0.f, 0.f};
    #pragma unroll
    for (int e = 0; e < 8; ++e) *(f32x4*)&rp_f[(e*256 + t)*4] = z;
    if (t < 32) l_s[t] = 0.f;
  }
  {
    const int row = t >> 3, c = t & 7;
    *(short8v*)&q_lds[row*64 + ((c ^ (row & 7))*8)] =
        *(const short8v*)&qb[row*64 + c*8];
  }
  #pragma unroll
  for (int e = 0; e < 2; ++e) {
    const int id = t + 256*e, row = id >> 3, c = id & 7;
    *(short8v*)&k_lds[row*64 + ((c ^ (row & 7))*8)] =
        *(const short8v*)&kb[(size_t)row*64 + c*8];
    *(short8v*)&vt_lds[row*64 + ((c ^ (row & 7))*8)] =
        *(const short8v*)&vtb[(size_t)row*2048 + c*8];
  }
  __syncthreads();

  const short8v aq0 = *(const short8v*)&q_lds[(ih*16 + lrow)*64 + ((g*8) ^ swz)];
  const short8v aq1 = *(const short8v*)&q_lds[(ih*16 + lrow)*64 + ((32 + g*8) ^ swz)];

  float rs_lo[4], rs_hi[4];
  #pragma unroll
  for (int r = 0; r < 4; ++r) {
    const int il = ih*16 + 4*g + r;
    rs_lo[r] = rsb[il*256 + 0];
    rs_hi[r] = rsb[il*256 + 255];
  }
  float ls_p[4]  = {0,0,0,0};
  float rpl_p[4] = {0,0,0,0};
  float rph_p[4] = {0,0,0,0};
  f32x4 ctx0 = {0,0,0,0}, ctx1 = {0,0,0,0};

  const int srow0 = t >> 3, sc = t & 7, srow1 = (t >> 3) + 32;

  for (int jt = 0; jt < 32; ++jt) {
    const int j0 = jt * 64;
    short* kl  = k_lds  + (jt & 1) * 4096;
    short* vl  = vt_lds + (jt & 1) * 4096;
    short* kln = k_lds  + ((jt & 1) ^ 1) * 4096;
    short* vln = vt_lds + ((jt & 1) ^ 1) * 4096;
    const bool have_next = (jt < 31);

    short8v stk0, stk1, stv0, stv1;
    if (have_next) {
      const int j0n = j0 + 64;
      stk0 = *(const short8v*)&kb[(size_t)(j0n + srow0)*64 + sc*8];
      stk1 = *(const short8v*)&kb[(size_t)(j0n + srow1)*64 + sc*8];
      stv0 = *(const short8v*)&vtb[(size_t)srow0*2048 + j0n + sc*8];
      stv1 = *(const short8v*)&vtb[(size_t)srow1*2048 + j0n + sc*8];
    }

    f32x4 c0 = {0,0,0,0}, c1 = {0,0,0,0};
    {
      const int jr0 = jh*32 + lrow, jr1 = jh*32 + 16 + lrow;
      const short8v b00 = *(const short8v*)&kl[jr0*64 + ((g*8) ^ swz)];
      const short8v b01 = *(const short8v*)&kl[jr0*64 + ((32 + g*8) ^ swz)];
      const short8v b10 = *(const short8v*)&kl[jr1*64 + ((g*8) ^ swz)];
      const short8v b11 = *(const short8v*)&kl[jr1*64 + ((32 + g*8) ^ swz)];
      c0 = MFMA16x16x32(aq0, b00, c0);
      c0 = MFMA16x16x32(aq1, b01, c0);
      c1 = MFMA16x16x32(aq0, b10, c1);
      c1 = MFMA16x16x32(aq1, b11, c1);
    }

    const float m0v = (1.0f - mb[j0 + jh*32 + lrow])      * -10000.0f;
    const float m1v = (1.0f - mb[j0 + jh*32 + 16 + lrow]) * -10000.0f;

    if (j0 <= i0 - 192) {
      #pragma unroll
      for (int r = 0; r < 4; ++r) {
        const int il  = ih*16 + 4*g + r;
        const int wsw = ((4*g + r) & 7) << 3;
        const float p0 = __expf(c0[r]*0.125f + rs_lo[r] + m0v - 8.0f);
        const float p1 = __expf(c1[r]*0.125f + rs_lo[r] + m1v - 8.0f);
        p_lds[il*64 + ((jh*32 + lrow) ^ wsw)]      = f2bf(p0);
        p_lds[il*64 + ((jh*32 + 16 + lrow) ^ wsw)] = f2bf(p1);
        rpl_p[r] += p0 + p1; ls_p[r] += p0 + p1;
      }
    } else if (j0 >= i0 + 159) {
      #pragma unroll
      for (int r = 0; r < 4; ++r) {
        const int il  = ih*16 + 4*g + r;
        const int wsw = ((4*g + r) & 7) << 3;
        const float p0 = __expf(c0[r]*0.125f + rs_hi[r] + m0v - 8.0f);
        const float p1 = __expf(c1[r]*0.125f + rs_hi[r] + m1v - 8.0f);
        p_lds[il*64 + ((jh*32 + lrow) ^ wsw)]      = f2bf(p0);
        p_lds[il*64 + ((jh*32 + 16 + lrow) ^ wsw)] = f2bf(p1);
        rph_p[r] += p0 + p1; ls_p[r] += p0 + p1;
      }
    } else {
      #pragma unroll
      for (int r = 0; r < 4; ++r) {
        const int il  = ih*16 + 4*g + r;
        const int gi  = i0 + il;
        const int wsw = ((4*g + r) & 7) << 3;
        {
          const int jl = jh*32 + lrow, gj = j0 + jl;
          int rel = gj - gi; rel = rel < -128 ? -128 : (rel > 127 ? 127 : rel);
          const int bk = rel + 128;
          const float p = __expf(c0[r]*0.125f + rsb[il*256 + bk] + m0v - 8.0f);
          p_lds[il*64 + (jl ^ wsw)] = f2bf(p);
          LDS_ATOMIC_ADD(&rp_f[il*256 + bk], p);
          ls_p[r] += p;
        }
        {
          const int jl = jh*32 + 16 + lrow, gj = j0 + jl;
          int rel = gj - gi; rel = rel < -128 ? -128 : (rel > 127 ? 127 : rel);
          const int bk = rel + 128;
          const float p = __expf(c1[r]*0.125f + rsb[il*256 + bk] + m1v - 8.0f);
          p_lds[il*64 + (jl ^ wsw)] = f2bf(p);
          LDS_ATOMIC_ADD(&rp_f[il*256 + bk], p);
          ls_p[r] += p;
        }
      }
    }
    __syncthreads();

    {
      const int prow = ih*16 + lrow;
      const short8v pa0 = *(const short8v*)&p_lds[prow*64 + ((g*8) ^ swz)];
      const short8v pa1 = *(const short8v*)&p_lds[prow*64 + ((32 + g*8) ^ swz)];
      const int d0 = jh*32 + lrow, d1 = jh*32 + 16 + lrow;
      const short8v vb00 = *(const short8v*)&vl[d0*64 + ((g*8) ^ swz)];
      const short8v vb01 = *(const short8v*)&vl[d0*64 + ((32 + g*8) ^ swz)];
      const short8v vb10 = *(const short8v*)&vl[d1*64 + ((g*8) ^ swz)];
      const short8v vb11 = *(const short8v*)&vl[d1*64 + ((32 + g*8) ^ swz)];
      ctx0 = MFMA16x16x32(pa0, vb00, ctx0);
      ctx0 = MFMA16x16x32(pa1, vb01, ctx0);
      ctx1 = MFMA16x16x32(pa0, vb10, ctx1);
      ctx1 = MFMA16x16x32(pa1, vb11, ctx1);
    }
    if (have_next) {
      *(short8v*)&kln[srow0*64 + ((sc ^ (srow0 & 7))*8)] = stk0;
      *(short8v*)&kln[srow1*64 + ((sc ^ (srow1 & 7))*8)] = stk1;
      *(short8v*)&vln[srow0*64 + ((sc ^ (srow0 & 7))*8)] = stv0;
      *(short8v*)&vln[srow1*64 + ((sc ^ (srow1 & 7))*8)] = stv1;
    }
    __syncthreads();
  }

  #pragma unroll
  for (int r = 0; r < 4; ++r) {
    float a = ls_p[r], bl = rpl_p[r], bhv = rph_p[r];
    #pragma unroll
    for (int m = 1; m < 16; m <<= 1) {
      a   += __shfl_xor(a, m);
      bl  += __shfl_xor(bl, m);
      bhv += __shfl_xor(bhv, m);
    }
    if (lrow == 0) {
      const int il = ih*16 + 4*g + r;
      LDS_ATOMIC_ADD(&l_s[il], a);
      LDS_ATOMIC_ADD(&rp_f[il*256 + 0], bl);
      LDS_ATOMIC_ADD(&rp_f[il*256 + 255], bhv);
    }
  }
  __syncthreads();

  #pragma unroll
  for (int e = 0; e < 4; ++e) {
    const int id = t + 256*e;
    const int row = id >> 5, c = id & 31;
    const float* src = &rp_f[row*256 + c*8];
    short8v v;
    #pragma unroll
    for (int i = 0; i < 8; ++i) v[i] = f2bf(src[i]);
    *(short8v*)&rp_bf[row*256 + ((c ^ (row & 7))*8)] = v;
  }
  __syncthreads();

  {
    const int arow = ih*16 + lrow;
    const int d0 = jh*32 + lrow, d1 = jh*32 + 16 + lrow;
    #pragma unroll
    for (int ks = 0; ks < 8; ++ks) {
      const short8v a  = *(const short8v*)&rp_bf[arow*256 + (((ks*4 + g) ^ (lrow & 7))*8)];
      const short8v b0 = *(const short8v*)&rvet[d0*256 + ks*32 + g*8];
      const short8v b1 = *(const short8v*)&rvet[d1*256 + ks*32 + g*8];
      ctx0 = MFMA16x16x32(a, b0, ctx0);
      ctx1 = MFMA16x16x32(a, b1, ctx1);
    }
  }

  #pragma unroll
  for (int r = 0; r < 4; ++r) {
    const int il = ih*16 + 4*g + r;
    const float invl = 1.0f / l_s[il];
    const int gi = i0 + il;
    out[(size_t)(b*2048 + gi)*768 + h*64 + jh*32 + lrow]      = ctx0[r] * invl;
    out[(size_t)(b*2048 + gi)*768 + h*64 + jh*32 + 16 + lrow] = ctx1[r] * invl;
  }
}

// ---------------- launcher ----------------
extern "C" void kernel_launch(void* const* d_in, const int* in_sizes, int n_in,
                              void* d_out, int out_size, void* d_ws, size_t ws_size,
                              hipStream_t stream) {
  const float* hs   = (const float*)d_in[0];
  const float* mask = (const float*)d_in[1];
  const float* Wq   = (const float*)d_in[2];
  const float* bq   = (const float*)d_in[3];
  const float* Wk   = (const float*)d_in[4];
  const float* bk   = (const float*)d_in[5];
  const float* Wv   = (const float*)d_in[6];
  const float* bv   = (const float*)d_in[7];
  const float* rke  = (const float*)d_in[8];
  const float* rve  = (const float*)d_in[9];
  // d_in[10] = indices, recomputed analytically on device.

  // Workspace layout (shorts unless noted). rs (fp32, written AFTER qkv
  // consumed hs splits) aliases hs_hi/hs_lo — temporal separation.
  //   [0 .. 50,331,648 B)   : union { rs f32 [49152*256] | hs_hi + hs_lo }
  //   then WT bf16 [3*768*768], qbf/kbf/vtbf [24*2048*64] each,
  //   rvet [64*256], rkeb [256*64].
  const size_t need_bytes = 72810496;
  if (ws_size < need_bytes) return;

  short* p     = (short*)d_ws;
  float* rsw   = (float*)d_ws;            // 12,582,912 f32 (aliases hs splits)
  short* hs_hi = p;                       // 3,145,728
  short* hs_lo = p + 3145728;
  short* wtb   = p + 25165824;            // 1,769,472
  short* qbf   = p + 26935296;            // 3,145,728
  short* kbf   = p + 30081024;
  short* vtbf  = p + 33226752;
  short* rvet  = p + 36372480;            // 16,384
  short* rkeb  = p + 36388864;            // 16,384
  float* out   = (float*)d_out;

  prep_hs_kernel<<<dim3(1536), dim3(256), 0, stream>>>(hs, hs_hi, hs_lo);
  prep_wt_kernel<<<dim3(12, 12, 3), dim3(256), 0, stream>>>(Wq, Wk, Wv, wtb);
  rvet_kernel<<<dim3(1), dim3(256), 0, stream>>>(rve, rke, rvet, rkeb);
  qkv_mfma_kernel<<<dim3(32, 6, 3), dim3(256), 0, stream>>>(
      hs_hi, hs_lo, wtb, bq, bk, bv, qbf, kbf, vtbf);
  rel_scores_mfma_kernel<<<dim3(192, 4), dim3(256), 0, stream>>>(qbf, rkeb, rsw);
  attn_mfma_kernel<<<dim3(64, 24), dim3(256), 0, stream>>>(
      qbf, kbf, vtbf, rsw, rvet, mask, out);
}

// Round 5
// 346.277 us; speedup vs baseline: 3.8029x; 1.0427x over previous
//
#include <hip/hip_runtime.h>
#include <hip/hip_bf16.h>
#include <math.h>

// Problem constants: B=2, S=2048, H=768, NH=12, D=64, R=256, MAX_REL=128
// BH = 24; QKV GEMM rows M = 4096.

#define LDS_ATOMIC_ADD(p, v) __hip_atomic_fetch_add((p), (v), __ATOMIC_RELAXED, __HIP_MEMORY_SCOPE_WORKGROUP)

typedef short short8v __attribute__((ext_vector_type(8)));
typedef short short4v __attribute__((ext_vector_type(4)));
typedef float f32x4 __attribute__((ext_vector_type(4)));

#define MFMA16x16x32(a, b, c) __builtin_amdgcn_mfma_f32_16x16x32_bf16((a), (b), (c), 0, 0, 0)

// float -> bf16 bits, round-to-nearest-even (values are finite here)
__device__ inline short f2bf(float f) {
  unsigned u = __float_as_uint(f);
  unsigned r = (u + 0x7FFFu + ((u >> 16) & 1u)) >> 16;
  return (short)r;
}
__device__ inline float bf2f(short b) {
  return __uint_as_float(((unsigned)(unsigned short)b) << 16);
}

// ---------------- Prep A: hs -> (hi, lo) bf16 split ----------------
__global__ __launch_bounds__(256) void prep_hs_kernel(
    const float* __restrict__ hs, short* __restrict__ hi, short* __restrict__ lo) {
  const size_t base = ((size_t)blockIdx.x * 256 + threadIdx.x) * 8;
  const float4 a = *(const float4*)&hs[base];
  const float4 b = *(const float4*)&hs[base + 4];
  float x[8] = {a.x, a.y, a.z, a.w, b.x, b.y, b.z, b.w};
  short8v h, l;
  #pragma unroll
  for (int i = 0; i < 8; ++i) {
    h[i] = f2bf(x[i]);
    l[i] = f2bf(x[i] - bf2f(h[i]));
  }
  *(short8v*)&hi[base] = h;
  *(short8v*)&lo[base] = l;
}

// ---------------- Prep B: W [768k][768n] -> WT bf16 [w][768n][768k] ----------------
__global__ __launch_bounds__(256) void prep_wt_kernel(
    const float* __restrict__ Wq, const float* __restrict__ Wk,
    const float* __restrict__ Wv, short* __restrict__ wt) {
  __shared__ float tile[64][65];
  const int t = threadIdx.x, tx = t & 15, ty = t >> 4;
  const int w = blockIdx.z;
  const float* W = (w == 0) ? Wq : (w == 1) ? Wk : Wv;
  const int k0 = blockIdx.x * 64, n0 = blockIdx.y * 64;
  #pragma unroll
  for (int rr = 0; rr < 4; ++rr) {
    const int kr = rr * 16 + ty;
    const float4 v = *(const float4*)&W[(size_t)(k0 + kr) * 768 + n0 + tx * 4];
    tile[kr][tx*4 + 0] = v.x; tile[kr][tx*4 + 1] = v.y;
    tile[kr][tx*4 + 2] = v.z; tile[kr][tx*4 + 3] = v.w;
  }
  __syncthreads();
  #pragma unroll
  for (int rr = 0; rr < 4; ++rr) {
    const int nr = rr * 16 + ty;
    short4v s;
    #pragma unroll
    for (int c = 0; c < 4; ++c) s[c] = f2bf(tile[tx*4 + c][nr]);
    *(short4v*)&wt[((size_t)w * 768 + n0 + nr) * 768 + k0 + tx * 4] = s;
  }
}

// ---------------- Prep C: rvet = rve^T bf16 [64][256]; rkeb = rke bf16 ----------------
__global__ __launch_bounds__(256) void rvet_kernel(
    const float* __restrict__ rve, const float* __restrict__ rke,
    short* __restrict__ rvet, short* __restrict__ rkeb) {
  const int t = threadIdx.x;
  #pragma unroll 4
  for (int e = 0; e < 64; ++e) {
    const int idx = e*256 + t;          // 16384 = 256 x 64
    const int r = idx >> 6, d = idx & 63;
    rvet[d*256 + r] = f2bf(rve[idx]);
    rkeb[idx]       = f2bf(rke[idx]);
  }
}

// ---------------- Kernel 1: QKV projection, MFMA bf16x2 (unchanged) ----------------
__global__ __launch_bounds__(256) void qkv_mfma_kernel(
    const short* __restrict__ hs_hi, const short* __restrict__ hs_lo,
    const short* __restrict__ wt,
    const float* __restrict__ bq, const float* __restrict__ bk,
    const float* __restrict__ bv,
    short* __restrict__ qbf, short* __restrict__ kbf, short* __restrict__ vtbf) {
  __shared__ short lds[3 * 8192];
  short* Ah = lds;                 // [128][64] swizzled
  short* Al = lds + 8192;
  short* Bt = lds + 16384;         // [128 n-rows][64 k]

  const int t = threadIdx.x, lane = t & 63, wv = t >> 6;
  const int wm = wv & 1, wn = wv >> 1;
  const int lrow = lane & 15, g = lane >> 4;
  const int m0 = blockIdx.x * 128, n0 = blockIdx.y * 128, w = blockIdx.z;
  const short* Bg = wt + (size_t)w * 768 * 768;
  const float* bias = (w == 0) ? bq : (w == 1) ? bk : bv;

  int srow[4], sc[4];
  #pragma unroll
  for (int e = 0; e < 4; ++e) {
    const int id = t + 256*e;
    srow[e] = id >> 3; sc[e] = id & 7;
  }

  #pragma unroll
  for (int e = 0; e < 4; ++e) {
    const int row = srow[e], c = sc[e];
    const int dst = row*64 + ((c ^ (row & 7)) * 8);
    *(short8v*)&Ah[dst] = *(const short8v*)&hs_hi[(size_t)(m0 + row)*768 + c*8];
    *(short8v*)&Al[dst] = *(const short8v*)&hs_lo[(size_t)(m0 + row)*768 + c*8];
    *(short8v*)&Bt[dst] = *(const short8v*)&Bg[(size_t)(n0 + row)*768 + c*8];
  }
  __syncthreads();

  f32x4 acc[4][4] = {};

  for (int kt = 0; kt < 12; ++kt) {
    short8v pa[4], pl[4], pb[4];
    const bool have_next = (kt < 11);
    if (have_next) {
      const int k0n = (kt + 1) * 64;
      #pragma unroll
      for (int e = 0; e < 4; ++e) {
        const int row = srow[e], c = sc[e];
        pa[e] = *(const short8v*)&hs_hi[(size_t)(m0 + row)*768 + k0n + c*8];
        pl[e] = *(const short8v*)&hs_lo[(size_t)(m0 + row)*768 + k0n + c*8];
        pb[e] = *(const short8v*)&Bg   [(size_t)(n0 + row)*768 + k0n + c*8];
      }
    }

    #pragma unroll
    for (int kc = 0; kc < 2; ++kc) {
      short8v af[4], alf[4], bfv[4];
      #pragma unroll
      for (int fm = 0; fm < 4; ++fm) {
        const int row = wm*64 + fm*16 + lrow;
        const int off = row*64 + (((kc*4 + g) ^ (row & 7)) * 8);
        af[fm]  = *(const short8v*)&Ah[off];
        alf[fm] = *(const short8v*)&Al[off];
      }
      #pragma unroll
      for (int fn = 0; fn < 4; ++fn) {
        const int row = wn*64 + fn*16 + lrow;
        bfv[fn] = *(const short8v*)&Bt[row*64 + (((kc*4 + g) ^ (row & 7)) * 8)];
      }
      #pragma unroll
      for (int fm = 0; fm < 4; ++fm)
        #pragma unroll
        for (int fn = 0; fn < 4; ++fn) {
          acc[fm][fn] = MFMA16x16x32(af[fm],  bfv[fn], acc[fm][fn]);
          acc[fm][fn] = MFMA16x16x32(alf[fm], bfv[fn], acc[fm][fn]);
        }
    }
    __syncthreads();
    if (have_next) {
      #pragma unroll
      for (int e = 0; e < 4; ++e) {
        const int row = srow[e], c = sc[e];
        const int dst = row*64 + ((c ^ (row & 7)) * 8);
        *(short8v*)&Ah[dst] = pa[e];
        *(short8v*)&Al[dst] = pl[e];
        *(short8v*)&Bt[dst] = pb[e];
      }
    }
    __syncthreads();
  }

  float bias_v[4];
  #pragma unroll
  for (int fn = 0; fn < 4; ++fn) bias_v[fn] = bias[n0 + wn*64 + fn*16 + lrow];

  #pragma unroll
  for (int fm = 0; fm < 4; ++fm) {
    #pragma unroll
    for (int r = 0; r < 4; ++r) {
      const int m = m0 + wm*64 + fm*16 + g*4 + r;
      const int b = m >> 11, s = m & 2047;
      #pragma unroll
      for (int fn = 0; fn < 4; ++fn) {
        const int n = n0 + wn*64 + fn*16 + lrow;
        const int h = n >> 6, d = n & 63;
        const size_t bh = (size_t)b*12 + h;
        const short sv = f2bf(acc[fm][fn][r] + bias_v[fn]);
        if (w == 0)      qbf [(bh*2048 + s)*64 + d] = sv;
        else if (w == 1) kbf [(bh*2048 + s)*64 + d] = sv;
        else             vtbf[(bh*64 + d)*2048 + s] = sv;
      }
    }
  }
}

// ---------------- Kernel 2: rel_scores = q @ rke^T * scale (MFMA, unchanged) ----------------
__global__ __launch_bounds__(256) void rel_scores_mfma_kernel(
    const short* __restrict__ qbf, const short* __restrict__ rkeb,
    float* __restrict__ rs) {
  __shared__ short Atile[256 * 64];   // 32 KB swizzled
  __shared__ short Btile[64 * 64];    //  8 KB swizzled
  const int t = threadIdx.x, lane = t & 63, wv = t >> 6;
  const int lrow = lane & 15, g = lane >> 4;
  const int m0 = blockIdx.x * 256, n0 = blockIdx.y * 64;

  #pragma unroll
  for (int e = 0; e < 8; ++e) {
    const int id = t + 256*e, row = id >> 3, c = id & 7;
    *(short8v*)&Atile[row*64 + ((c ^ (row & 7)) * 8)] =
        *(const short8v*)&qbf[(size_t)(m0 + row)*64 + c*8];
  }
  #pragma unroll
  for (int e = 0; e < 2; ++e) {
    const int id = t + 256*e, row = id >> 3, c = id & 7;
    *(short8v*)&Btile[row*64 + ((c ^ (row & 7)) * 8)] =
        *(const short8v*)&rkeb[(size_t)(n0 + row)*64 + c*8];
  }
  __syncthreads();

  f32x4 acc[4][4] = {};
  #pragma unroll
  for (int kc = 0; kc < 2; ++kc) {
    short8v af[4], bfv[4];
    #pragma unroll
    for (int fm = 0; fm < 4; ++fm) {
      const int row = wv*64 + fm*16 + lrow;
      af[fm] = *(const short8v*)&Atile[row*64 + (((kc*4 + g) ^ (row & 7)) * 8)];
    }
    #pragma unroll
    for (int fn = 0; fn < 4; ++fn) {
      const int row = fn*16 + lrow;
      bfv[fn] = *(const short8v*)&Btile[row*64 + (((kc*4 + g) ^ (row & 7)) * 8)];
    }
    #pragma unroll
    for (int fm = 0; fm < 4; ++fm)
      #pragma unroll
      for (int fn = 0; fn < 4; ++fn)
        acc[fm][fn] = MFMA16x16x32(af[fm], bfv[fn], acc[fm][fn]);
  }

  #pragma unroll
  for (int fm = 0; fm < 4; ++fm)
    #pragma unroll
    for (int r = 0; r < 4; ++r) {
      const int m = m0 + wv*64 + fm*16 + g*4 + r;
      #pragma unroll
      for (int fn = 0; fn < 4; ++fn)
        rs[(size_t)m*256 + n0 + fn*16 + lrow] = acc[fm][fn][r] * 0.125f;
    }
}

// ---------------- Kernel 3: fused attention, MFMA bf16 ----------------
// LDS cut to 53376 B -> 3 blocks/CU (was 74240 -> 2). Single-buffered K/V
// with re-derived 2-barrier schedule:
//   tile t: [write v(t) from regs] [issue loads k(t+1),v(t+1)] QK(k_buf)
//           p-write/atomics B1 [write k(t+1)] PV(v_buf,p) B2
// k-write post-B1 (k(t) reads all pre-B1); v-write post-B2(t-1).
// p_lds aliases q_lds (q dead after register hoist; extra prologue barrier).
__global__ __launch_bounds__(256) void attn_mfma_kernel(
    const short* __restrict__ qbf, const short* __restrict__ kbf,
    const short* __restrict__ vtbf, const float* __restrict__ rs,
    const short* __restrict__ rvet, const float* __restrict__ mask,
    float* __restrict__ out) {
  __shared__ __align__(16) char smem[53376];
  float* rp_f   = (float*)smem;                 // [32*256] f32  32768 B
  short* k_lds  = (short*)(smem + 32768);       // [64*64]        8192 B
  short* vt_lds = (short*)(smem + 40960);       // [64*64]        8192 B
  short* qp_lds = (short*)(smem + 49152);       // [32*64] q,then p  4096 B
  float* l_s    = (float*)(smem + 53248);       // [32]            128 B
  short* rp_bf  = (short*)(smem + 32768);       // alias k+v, [32*256] bf16

  const int t    = threadIdx.x;
  const int lane = t & 63, wv = t >> 6;
  const int ih   = wv & 1, jh = wv >> 1;
  const int lrow = lane & 15, g = lane >> 4;
  const int swz  = (lrow & 7) << 3;

  const int bh = blockIdx.y, b = bh / 12, h = bh % 12;
  const int i0 = blockIdx.x * 32;

  const short* qb  = qbf  + ((size_t)bh*2048 + i0)*64;
  const short* kb  = kbf  + (size_t)bh*2048*64;
  const short* vtb = vtbf + (size_t)bh*64*2048;
  const float* rsb = rs   + ((size_t)bh*2048 + i0)*256;
  const float* mb  = mask + (size_t)b*2048;

  // zero rp / l
  {
    f32x4 z = {0.f, 0.f, 0.f, 0.f};
    #pragma unroll
    for (int e = 0; e < 8; ++e) *(f32x4*)&rp_f[(e*256 + t)*4] = z;
    if (t < 32) l_s[t] = 0.f;
  }
  // stage q (32 rows x 8 chunks)
  {
    const int row = t >> 3, c = t & 7;
    *(short8v*)&qp_lds[row*64 + ((c ^ (row & 7))*8)] =
        *(const short8v*)&qb[row*64 + c*8];
  }
  // stage k/vt tile 0 (single buffers)
  #pragma unroll
  for (int e = 0; e < 2; ++e) {
    const int id = t + 256*e, row = id >> 3, c = id & 7;
    *(short8v*)&k_lds[row*64 + ((c ^ (row & 7))*8)] =
        *(const short8v*)&kb[(size_t)row*64 + c*8];
    *(short8v*)&vt_lds[row*64 + ((c ^ (row & 7))*8)] =
        *(const short8v*)&vtb[(size_t)row*2048 + c*8];
  }
  __syncthreads();                       // P1: staging visible

  // hoisted Q A-fragments (loop-invariant)
  const short8v aq0 = *(const short8v*)&qp_lds[(ih*16 + lrow)*64 + ((g*8) ^ swz)];
  const short8v aq1 = *(const short8v*)&qp_lds[(ih*16 + lrow)*64 + ((32 + g*8) ^ swz)];
  __syncthreads();                       // P2: q reads done; p may overwrite

  float rs_lo[4], rs_hi[4];
  #pragma unroll
  for (int r = 0; r < 4; ++r) {
    const int il = ih*16 + 4*g + r;
    rs_lo[r] = rsb[il*256 + 0];
    rs_hi[r] = rsb[il*256 + 255];
  }
  float ls_p[4]  = {0,0,0,0};
  float rpl_p[4] = {0,0,0,0};
  float rph_p[4] = {0,0,0,0};
  f32x4 ctx0 = {0,0,0,0}, ctx1 = {0,0,0,0};

  const int srow0 = t >> 3, sc = t & 7, srow1 = (t >> 3) + 32;
  short8v stk0, stk1, stv0, stv1;

  for (int jt = 0; jt < 32; ++jt) {
    const int j0 = jt * 64;
    const bool have_next = (jt < 31);

    // v(jt) from regs -> LDS (post-B2(jt-1); all PV reads of v(jt-1) done)
    if (jt > 0) {
      *(short8v*)&vt_lds[srow0*64 + ((sc ^ (srow0 & 7))*8)] = stv0;
      *(short8v*)&vt_lds[srow1*64 + ((sc ^ (srow1 & 7))*8)] = stv1;
    }
    if (have_next) {                 // issue next-tile global loads
      const int j0n = j0 + 64;
      stk0 = *(const short8v*)&kb[(size_t)(j0n + srow0)*64 + sc*8];
      stk1 = *(const short8v*)&kb[(size_t)(j0n + srow1)*64 + sc*8];
      stv0 = *(const short8v*)&vtb[(size_t)srow0*2048 + j0n + sc*8];
      stv1 = *(const short8v*)&vtb[(size_t)srow1*2048 + j0n + sc*8];
    }

    // --- QK^T: 2 C-tiles (n=0,1), K=64 in 2 steps ---
    f32x4 c0 = {0,0,0,0}, c1 = {0,0,0,0};
    {
      const int jr0 = jh*32 + lrow, jr1 = jh*32 + 16 + lrow;
      const short8v b00 = *(const short8v*)&k_lds[jr0*64 + ((g*8) ^ swz)];
      const short8v b01 = *(const short8v*)&k_lds[jr0*64 + ((32 + g*8) ^ swz)];
      const short8v b10 = *(const short8v*)&k_lds[jr1*64 + ((g*8) ^ swz)];
      const short8v b11 = *(const short8v*)&k_lds[jr1*64 + ((32 + g*8) ^ swz)];
      c0 = MFMA16x16x32(aq0, b00, c0);
      c0 = MFMA16x16x32(aq1, b01, c0);
      c1 = MFMA16x16x32(aq0, b10, c1);
      c1 = MFMA16x16x32(aq1, b11, c1);
    }

    const float m0v = (1.0f - mb[j0 + jh*32 + lrow])      * -10000.0f;
    const float m1v = (1.0f - mb[j0 + jh*32 + 16 + lrow]) * -10000.0f;

    if (j0 <= i0 - 192) {            // whole tile -> bucket 0
      #pragma unroll
      for (int r = 0; r < 4; ++r) {
        const int il  = ih*16 + 4*g + r;
        const int wsw = ((4*g + r) & 7) << 3;
        const float p0 = __expf(c0[r]*0.125f + rs_lo[r] + m0v - 8.0f);
        const float p1 = __expf(c1[r]*0.125f + rs_lo[r] + m1v - 8.0f);
        qp_lds[il*64 + ((jh*32 + lrow) ^ wsw)]      = f2bf(p0);
        qp_lds[il*64 + ((jh*32 + 16 + lrow) ^ wsw)] = f2bf(p1);
        rpl_p[r] += p0 + p1; ls_p[r] += p0 + p1;
      }
    } else if (j0 >= i0 + 159) {     // whole tile -> bucket 255
      #pragma unroll
      for (int r = 0; r < 4; ++r) {
        const int il  = ih*16 + 4*g + r;
        const int wsw = ((4*g + r) & 7) << 3;
        const float p0 = __expf(c0[r]*0.125f + rs_hi[r] + m0v - 8.0f);
        const float p1 = __expf(c1[r]*0.125f + rs_hi[r] + m1v - 8.0f);
        qp_lds[il*64 + ((jh*32 + lrow) ^ wsw)]      = f2bf(p0);
        qp_lds[il*64 + ((jh*32 + 16 + lrow) ^ wsw)] = f2bf(p1);
        rph_p[r] += p0 + p1; ls_p[r] += p0 + p1;
      }
    } else {                         // band: per-element bucket
      #pragma unroll
      for (int r = 0; r < 4; ++r) {
        const int il  = ih*16 + 4*g + r;
        const int gi  = i0 + il;
        const int wsw = ((4*g + r) & 7) << 3;
        {
          const int jl = jh*32 + lrow, gj = j0 + jl;
          int rel = gj - gi; rel = rel < -128 ? -128 : (rel > 127 ? 127 : rel);
          const int bk = rel + 128;
          const float p = __expf(c0[r]*0.125f + rsb[il*256 + bk] + m0v - 8.0f);
          qp_lds[il*64 + (jl ^ wsw)] = f2bf(p);
          LDS_ATOMIC_ADD(&rp_f[il*256 + bk], p);
          ls_p[r] += p;
        }
        {
          const int jl = jh*32 + 16 + lrow, gj = j0 + jl;
          int rel = gj - gi; rel = rel < -128 ? -128 : (rel > 127 ? 127 : rel);
          const int bk = rel + 128;
          const float p = __expf(c1[r]*0.125f + rsb[il*256 + bk] + m1v - 8.0f);
          qp_lds[il*64 + (jl ^ wsw)] = f2bf(p);
          LDS_ATOMIC_ADD(&rp_f[il*256 + bk], p);
          ls_p[r] += p;
        }
      }
    }
    __syncthreads();                 // B1: p visible; all k(jt) reads done

    // k(jt+1) from regs -> LDS (k(jt) dead)
    if (have_next) {
      *(short8v*)&k_lds[srow0*64 + ((sc ^ (srow0 & 7))*8)] = stk0;
      *(short8v*)&k_lds[srow1*64 + ((sc ^ (srow1 & 7))*8)] = stk1;
    }

    // --- PV: ctx[i][d] += P[i][:] @ V[:, d] ---
    {
      const int prow = ih*16 + lrow;
      const short8v pa0 = *(const short8v*)&qp_lds[prow*64 + ((g*8) ^ swz)];
      const short8v pa1 = *(const short8v*)&qp_lds[prow*64 + ((32 + g*8) ^ swz)];
      const int d0 = jh*32 + lrow, d1 = jh*32 + 16 + lrow;
      const short8v vb00 = *(const short8v*)&vt_lds[d0*64 + ((g*8) ^ swz)];
      const short8v vb01 = *(const short8v*)&vt_lds[d0*64 + ((32 + g*8) ^ swz)];
      const short8v vb10 = *(const short8v*)&vt_lds[d1*64 + ((g*8) ^ swz)];
      const short8v vb11 = *(const short8v*)&vt_lds[d1*64 + ((32 + g*8) ^ swz)];
      ctx0 = MFMA16x16x32(pa0, vb00, ctx0);
      ctx0 = MFMA16x16x32(pa1, vb01, ctx0);
      ctx1 = MFMA16x16x32(pa0, vb10, ctx1);
      ctx1 = MFMA16x16x32(pa1, vb11, ctx1);
    }
    __syncthreads();                 // B2: PV reads done; k(jt+1) visible
  }

  // --- fold per-lane partials ---
  #pragma unroll
  for (int r = 0; r < 4; ++r) {
    float a = ls_p[r], bl = rpl_p[r], bhv = rph_p[r];
    #pragma unroll
    for (int m = 1; m < 16; m <<= 1) {
      a   += __shfl_xor(a, m);
      bl  += __shfl_xor(bl, m);
      bhv += __shfl_xor(bhv, m);
    }
    if (lrow == 0) {
      const int il = ih*16 + 4*g + r;
      LDS_ATOMIC_ADD(&l_s[il], a);
      LDS_ATOMIC_ADD(&rp_f[il*256 + 0], bl);
      LDS_ATOMIC_ADD(&rp_f[il*256 + 255], bhv);
    }
  }
  __syncthreads();

  // --- convert rp (f32) -> rp_bf (A layout, aliases k+v LDS) ---
  #pragma unroll
  for (int e = 0; e < 4; ++e) {
    const int id = t + 256*e;
    const int row = id >> 5, c = id & 31;
    const float* src = &rp_f[row*256 + c*8];
    short8v v;
    #pragma unroll
    for (int i = 0; i < 8; ++i) v[i] = f2bf(src[i]);
    *(short8v*)&rp_bf[row*256 + ((c ^ (row & 7))*8)] = v;
  }
  __syncthreads();

  // --- rel-value epilogue: ctx += rp @ rve (K=256) ---
  {
    const int arow = ih*16 + lrow;
    const int d0 = jh*32 + lrow, d1 = jh*32 + 16 + lrow;
    #pragma unroll
    for (int ks = 0; ks < 8; ++ks) {
      const short8v a  = *(const short8v*)&rp_bf[arow*256 + (((ks*4 + g) ^ (lrow & 7))*8)];
      const short8v b0 = *(const short8v*)&rvet[d0*256 + ks*32 + g*8];
      const short8v b1 = *(const short8v*)&rvet[d1*256 + ks*32 + g*8];
      ctx0 = MFMA16x16x32(a, b0, ctx0);
      ctx1 = MFMA16x16x32(a, b1, ctx1);
    }
  }

  // --- normalize + store ---
  #pragma unroll
  for (int r = 0; r < 4; ++r) {
    const int il = ih*16 + 4*g + r;
    const float invl = 1.0f / l_s[il];
    const int gi = i0 + il;
    out[(size_t)(b*2048 + gi)*768 + h*64 + jh*32 + lrow]      = ctx0[r] * invl;
    out[(size_t)(b*2048 + gi)*768 + h*64 + jh*32 + 16 + lrow] = ctx1[r] * invl;
  }
}

// ---------------- launcher ----------------
extern "C" void kernel_launch(void* const* d_in, const int* in_sizes, int n_in,
                              void* d_out, int out_size, void* d_ws, size_t ws_size,
                              hipStream_t stream) {
  const float* hs   = (const float*)d_in[0];
  const float* mask = (const float*)d_in[1];
  const float* Wq   = (const float*)d_in[2];
  const float* bq   = (const float*)d_in[3];
  const float* Wk   = (const float*)d_in[4];
  const float* bk   = (const float*)d_in[5];
  const float* Wv   = (const float*)d_in[6];
  const float* bv   = (const float*)d_in[7];
  const float* rke  = (const float*)d_in[8];
  const float* rve  = (const float*)d_in[9];
  // d_in[10] = indices, recomputed analytically on device.

  const size_t need_bytes = 72810496;
  if (ws_size < need_bytes) return;

  short* p     = (short*)d_ws;
  float* rsw   = (float*)d_ws;            // 12,582,912 f32 (aliases hs splits)
  short* hs_hi = p;                       // 3,145,728
  short* hs_lo = p + 3145728;
  short* wtb   = p + 25165824;            // 1,769,472
  short* qbf   = p + 26935296;            // 3,145,728
  short* kbf   = p + 30081024;
  short* vtbf  = p + 33226752;
  short* rvet  = p + 36372480;            // 16,384
  short* rkeb  = p + 36388864;            // 16,384
  float* out   = (float*)d_out;

  prep_hs_kernel<<<dim3(1536), dim3(256), 0, stream>>>(hs, hs_hi, hs_lo);
  prep_wt_kernel<<<dim3(12, 12, 3), dim3(256), 0, stream>>>(Wq, Wk, Wv, wtb);
  rvet_kernel<<<dim3(1), dim3(256), 0, stream>>>(rve, rke, rvet, rkeb);
  qkv_mfma_kernel<<<dim3(32, 6, 3), dim3(256), 0, stream>>>(
      hs_hi, hs_lo, wtb, bq, bk, bv, qbf, kbf, vtbf);
  rel_scores_mfma_kernel<<<dim3(192, 4), dim3(256), 0, stream>>>(qbf, rkeb, rsw);
  attn_mfma_kernel<<<dim3(64, 24), dim3(256), 0, stream>>>(
      qbf, kbf, vtbf, rsw, rvet, mask, out);
}

// Round 6
// 289.487 us; speedup vs baseline: 4.5489x; 1.1962x over previous
//
#include <hip/hip_runtime.h>
#include <hip/hip_bf16.h>
#include <math.h>

// Problem constants: B=2, S=2048, H=768, NH=12, D=64, R=256, MAX_REL=128
// BH = 24; QKV GEMM rows M = 4096.

#define LDS_ATOMIC_ADD(p, v) __hip_atomic_fetch_add((p), (v), __ATOMIC_RELAXED, __HIP_MEMORY_SCOPE_WORKGROUP)

typedef short short8v __attribute__((ext_vector_type(8)));
typedef short short4v __attribute__((ext_vector_type(4)));
typedef float f32x4 __attribute__((ext_vector_type(4)));

#define MFMA16x16x32(a, b, c) __builtin_amdgcn_mfma_f32_16x16x32_bf16((a), (b), (c), 0, 0, 0)

// float -> bf16 bits, round-to-nearest-even (values are finite here)
__device__ inline short f2bf(float f) {
  unsigned u = __float_as_uint(f);
  unsigned r = (u + 0x7FFFu + ((u >> 16) & 1u)) >> 16;
  return (short)r;
}
__device__ inline float bf2f(short b) {
  return __uint_as_float(((unsigned)(unsigned short)b) << 16);
}

// ---------------- Prep A: hs -> (hi, lo) bf16 split ----------------
__global__ __launch_bounds__(256) void prep_hs_kernel(
    const float* __restrict__ hs, short* __restrict__ hi, short* __restrict__ lo) {
  const size_t base = ((size_t)blockIdx.x * 256 + threadIdx.x) * 8;
  const float4 a = *(const float4*)&hs[base];
  const float4 b = *(const float4*)&hs[base + 4];
  float x[8] = {a.x, a.y, a.z, a.w, b.x, b.y, b.z, b.w};
  short8v h, l;
  #pragma unroll
  for (int i = 0; i < 8; ++i) {
    h[i] = f2bf(x[i]);
    l[i] = f2bf(x[i] - bf2f(h[i]));
  }
  *(short8v*)&hi[base] = h;
  *(short8v*)&lo[base] = l;
}

// ---------------- Prep B: W [768k][768n] -> WT bf16 [w][768n][768k] ----------------
__global__ __launch_bounds__(256) void prep_wt_kernel(
    const float* __restrict__ Wq, const float* __restrict__ Wk,
    const float* __restrict__ Wv, short* __restrict__ wt) {
  __shared__ float tile[64][65];
  const int t = threadIdx.x, tx = t & 15, ty = t >> 4;
  const int w = blockIdx.z;
  const float* W = (w == 0) ? Wq : (w == 1) ? Wk : Wv;
  const int k0 = blockIdx.x * 64, n0 = blockIdx.y * 64;
  #pragma unroll
  for (int rr = 0; rr < 4; ++rr) {
    const int kr = rr * 16 + ty;
    const float4 v = *(const float4*)&W[(size_t)(k0 + kr) * 768 + n0 + tx * 4];
    tile[kr][tx*4 + 0] = v.x; tile[kr][tx*4 + 1] = v.y;
    tile[kr][tx*4 + 2] = v.z; tile[kr][tx*4 + 3] = v.w;
  }
  __syncthreads();
  #pragma unroll
  for (int rr = 0; rr < 4; ++rr) {
    const int nr = rr * 16 + ty;
    short4v s;
    #pragma unroll
    for (int c = 0; c < 4; ++c) s[c] = f2bf(tile[tx*4 + c][nr]);
    *(short4v*)&wt[((size_t)w * 768 + n0 + nr) * 768 + k0 + tx * 4] = s;
  }
}

// ---------------- Prep C: rvet = rve^T bf16 [64][256]; rkeb = rke bf16 ----------------
__global__ __launch_bounds__(256) void rvet_kernel(
    const float* __restrict__ rve, const float* __restrict__ rke,
    short* __restrict__ rvet, short* __restrict__ rkeb) {
  const int t = threadIdx.x;
  #pragma unroll 4
  for (int e = 0; e < 64; ++e) {
    const int idx = e*256 + t;          // 16384 = 256 x 64
    const int r = idx >> 6, d = idx & 63;
    rvet[d*256 + r] = f2bf(rve[idx]);
    rkeb[idx]       = f2bf(rke[idx]);
  }
}

// ---------------- Kernel 1: QKV projection, MFMA bf16x2 (unchanged) ----------------
__global__ __launch_bounds__(256) void qkv_mfma_kernel(
    const short* __restrict__ hs_hi, const short* __restrict__ hs_lo,
    const short* __restrict__ wt,
    const float* __restrict__ bq, const float* __restrict__ bk,
    const float* __restrict__ bv,
    short* __restrict__ qbf, short* __restrict__ kbf, short* __restrict__ vtbf) {
  __shared__ short lds[3 * 8192];
  short* Ah = lds;                 // [128][64] swizzled
  short* Al = lds + 8192;
  short* Bt = lds + 16384;         // [128 n-rows][64 k]

  const int t = threadIdx.x, lane = t & 63, wv = t >> 6;
  const int wm = wv & 1, wn = wv >> 1;
  const int lrow = lane & 15, g = lane >> 4;
  const int m0 = blockIdx.x * 128, n0 = blockIdx.y * 128, w = blockIdx.z;
  const short* Bg = wt + (size_t)w * 768 * 768;
  const float* bias = (w == 0) ? bq : (w == 1) ? bk : bv;

  int srow[4], sc[4];
  #pragma unroll
  for (int e = 0; e < 4; ++e) {
    const int id = t + 256*e;
    srow[e] = id >> 3; sc[e] = id & 7;
  }

  #pragma unroll
  for (int e = 0; e < 4; ++e) {
    const int row = srow[e], c = sc[e];
    const int dst = row*64 + ((c ^ (row & 7)) * 8);
    *(short8v*)&Ah[dst] = *(const short8v*)&hs_hi[(size_t)(m0 + row)*768 + c*8];
    *(short8v*)&Al[dst] = *(const short8v*)&hs_lo[(size_t)(m0 + row)*768 + c*8];
    *(short8v*)&Bt[dst] = *(const short8v*)&Bg[(size_t)(n0 + row)*768 + c*8];
  }
  __syncthreads();

  f32x4 acc[4][4] = {};

  for (int kt = 0; kt < 12; ++kt) {
    short8v pa[4], pl[4], pb[4];
    const bool have_next = (kt < 11);
    if (have_next) {
      const int k0n = (kt + 1) * 64;
      #pragma unroll
      for (int e = 0; e < 4; ++e) {
        const int row = srow[e], c = sc[e];
        pa[e] = *(const short8v*)&hs_hi[(size_t)(m0 + row)*768 + k0n + c*8];
        pl[e] = *(const short8v*)&hs_lo[(size_t)(m0 + row)*768 + k0n + c*8];
        pb[e] = *(const short8v*)&Bg   [(size_t)(n0 + row)*768 + k0n + c*8];
      }
    }

    #pragma unroll
    for (int kc = 0; kc < 2; ++kc) {
      short8v af[4], alf[4], bfv[4];
      #pragma unroll
      for (int fm = 0; fm < 4; ++fm) {
        const int row = wm*64 + fm*16 + lrow;
        const int off = row*64 + (((kc*4 + g) ^ (row & 7)) * 8);
        af[fm]  = *(const short8v*)&Ah[off];
        alf[fm] = *(const short8v*)&Al[off];
      }
      #pragma unroll
      for (int fn = 0; fn < 4; ++fn) {
        const int row = wn*64 + fn*16 + lrow;
        bfv[fn] = *(const short8v*)&Bt[row*64 + (((kc*4 + g) ^ (row & 7)) * 8)];
      }
      #pragma unroll
      for (int fm = 0; fm < 4; ++fm)
        #pragma unroll
        for (int fn = 0; fn < 4; ++fn) {
          acc[fm][fn] = MFMA16x16x32(af[fm],  bfv[fn], acc[fm][fn]);
          acc[fm][fn] = MFMA16x16x32(alf[fm], bfv[fn], acc[fm][fn]);
        }
    }
    __syncthreads();
    if (have_next) {
      #pragma unroll
      for (int e = 0; e < 4; ++e) {
        const int row = srow[e], c = sc[e];
        const int dst = row*64 + ((c ^ (row & 7)) * 8);
        *(short8v*)&Ah[dst] = pa[e];
        *(short8v*)&Al[dst] = pl[e];
        *(short8v*)&Bt[dst] = pb[e];
      }
    }
    __syncthreads();
  }

  float bias_v[4];
  #pragma unroll
  for (int fn = 0; fn < 4; ++fn) bias_v[fn] = bias[n0 + wn*64 + fn*16 + lrow];

  #pragma unroll
  for (int fm = 0; fm < 4; ++fm) {
    #pragma unroll
    for (int r = 0; r < 4; ++r) {
      const int m = m0 + wm*64 + fm*16 + g*4 + r;
      const int b = m >> 11, s = m & 2047;
      #pragma unroll
      for (int fn = 0; fn < 4; ++fn) {
        const int n = n0 + wn*64 + fn*16 + lrow;
        const int h = n >> 6, d = n & 63;
        const size_t bh = (size_t)b*12 + h;
        const short sv = f2bf(acc[fm][fn][r] + bias_v[fn]);
        if (w == 0)      qbf [(bh*2048 + s)*64 + d] = sv;
        else if (w == 1) kbf [(bh*2048 + s)*64 + d] = sv;
        else             vtbf[(bh*64 + d)*2048 + s] = sv;
      }
    }
  }
}

// ---------------- Kernel 2: rel_scores = q @ rke^T * scale (MFMA, unchanged) ----------------
__global__ __launch_bounds__(256) void rel_scores_mfma_kernel(
    const short* __restrict__ qbf, const short* __restrict__ rkeb,
    float* __restrict__ rs) {
  __shared__ short Atile[256 * 64];   // 32 KB swizzled
  __shared__ short Btile[64 * 64];    //  8 KB swizzled
  const int t = threadIdx.x, lane = t & 63, wv = t >> 6;
  const int lrow = lane & 15, g = lane >> 4;
  const int m0 = blockIdx.x * 256, n0 = blockIdx.y * 64;

  #pragma unroll
  for (int e = 0; e < 8; ++e) {
    const int id = t + 256*e, row = id >> 3, c = id & 7;
    *(short8v*)&Atile[row*64 + ((c ^ (row & 7)) * 8)] =
        *(const short8v*)&qbf[(size_t)(m0 + row)*64 + c*8];
  }
  #pragma unroll
  for (int e = 0; e < 2; ++e) {
    const int id = t + 256*e, row = id >> 3, c = id & 7;
    *(short8v*)&Btile[row*64 + ((c ^ (row & 7)) * 8)] =
        *(const short8v*)&rkeb[(size_t)(n0 + row)*64 + c*8];
  }
  __syncthreads();

  f32x4 acc[4][4] = {};
  #pragma unroll
  for (int kc = 0; kc < 2; ++kc) {
    short8v af[4], bfv[4];
    #pragma unroll
    for (int fm = 0; fm < 4; ++fm) {
      const int row = wv*64 + fm*16 + lrow;
      af[fm] = *(const short8v*)&Atile[row*64 + (((kc*4 + g) ^ (row & 7)) * 8)];
    }
    #pragma unroll
    for (int fn = 0; fn < 4; ++fn) {
      const int row = fn*16 + lrow;
      bfv[fn] = *(const short8v*)&Btile[row*64 + (((kc*4 + g) ^ (row & 7)) * 8)];
    }
    #pragma unroll
    for (int fm = 0; fm < 4; ++fm)
      #pragma unroll
      for (int fn = 0; fn < 4; ++fn)
        acc[fm][fn] = MFMA16x16x32(af[fm], bfv[fn], acc[fm][fn]);
  }

  #pragma unroll
  for (int fm = 0; fm < 4; ++fm)
    #pragma unroll
    for (int r = 0; r < 4; ++r) {
      const int m = m0 + wv*64 + fm*16 + g*4 + r;
      #pragma unroll
      for (int fn = 0; fn < 4; ++fn)
        rs[(size_t)m*256 + n0 + fn*16 + lrow] = acc[fm][fn][r] * 0.125f;
    }
}

// ---------------- Kernel 3: fused attention, MFMA bf16 ----------------
// rel_probs insight: interior buckets (1..254) receive exactly ONE (i,j)
// each (j = i+bk-128) -> single-writer plain bf16 stores, NO atomics, no
// f32 array, no conversion pass. Edges (0,255) accumulate in registers and
// fold once at the end. LDS = 36.4 KB -> 4 blocks/CU.
// Single-buffered K/V, 2-barrier schedule as round 5.
__global__ __launch_bounds__(256) void attn_mfma_kernel(
    const short* __restrict__ qbf, const short* __restrict__ kbf,
    const short* __restrict__ vtbf, const float* __restrict__ rs,
    const short* __restrict__ rvet, const float* __restrict__ mask,
    float* __restrict__ out) {
  __shared__ __align__(16) char smem[37248];
  short* rp_bf  = (short*)smem;                 // [32*256] bf16, swizzled  16384 B
  short* k_lds  = (short*)(smem + 16384);       // [64*64]                   8192 B
  short* vt_lds = (short*)(smem + 24576);       // [64*64]                   8192 B
  short* qp_lds = (short*)(smem + 32768);       // [32*64] q, then p         4096 B
  float* l_s    = (float*)(smem + 36864);       // [32]                       128 B
  float* edge_f = (float*)(smem + 36992);       // [32][2]                    256 B

  const int t    = threadIdx.x;
  const int lane = t & 63, wv = t >> 6;
  const int ih   = wv & 1, jh = wv >> 1;
  const int lrow = lane & 15, g = lane >> 4;
  const int swz  = (lrow & 7) << 3;

  const int bh = blockIdx.y, b = bh / 12, h = bh % 12;
  const int i0 = blockIdx.x * 32;

  const short* qb  = qbf  + ((size_t)bh*2048 + i0)*64;
  const short* kb  = kbf  + (size_t)bh*2048*64;
  const short* vtb = vtbf + (size_t)bh*64*2048;
  const float* rsb = rs   + ((size_t)bh*2048 + i0)*256;
  const float* mb  = mask + (size_t)b*2048;

  // zero rp_bf (16 KB) + l/edge
  {
    const short8v z8 = {0,0,0,0,0,0,0,0};
    #pragma unroll
    for (int e = 0; e < 4; ++e) *(short8v*)&rp_bf[(e*256 + t)*8] = z8;
    if (t < 32) { l_s[t] = 0.f; edge_f[2*t] = 0.f; edge_f[2*t+1] = 0.f; }
  }
  // stage q (32 rows x 8 chunks)
  {
    const int row = t >> 3, c = t & 7;
    *(short8v*)&qp_lds[row*64 + ((c ^ (row & 7))*8)] =
        *(const short8v*)&qb[row*64 + c*8];
  }
  // stage k/vt tile 0 (single buffers)
  #pragma unroll
  for (int e = 0; e < 2; ++e) {
    const int id = t + 256*e, row = id >> 3, c = id & 7;
    *(short8v*)&k_lds[row*64 + ((c ^ (row & 7))*8)] =
        *(const short8v*)&kb[(size_t)row*64 + c*8];
    *(short8v*)&vt_lds[row*64 + ((c ^ (row & 7))*8)] =
        *(const short8v*)&vtb[(size_t)row*2048 + c*8];
  }
  __syncthreads();                       // P1: staging visible

  // hoisted Q A-fragments (loop-invariant)
  const short8v aq0 = *(const short8v*)&qp_lds[(ih*16 + lrow)*64 + ((g*8) ^ swz)];
  const short8v aq1 = *(const short8v*)&qp_lds[(ih*16 + lrow)*64 + ((32 + g*8) ^ swz)];
  __syncthreads();                       // P2: q reads done; p may overwrite

  float rs_lo[4], rs_hi[4];
  #pragma unroll
  for (int r = 0; r < 4; ++r) {
    const int il = ih*16 + 4*g + r;
    rs_lo[r] = rsb[il*256 + 0];
    rs_hi[r] = rsb[il*256 + 255];
  }
  float ls_p[4]  = {0,0,0,0};
  float rpl_p[4] = {0,0,0,0};
  float rph_p[4] = {0,0,0,0};
  f32x4 ctx0 = {0,0,0,0}, ctx1 = {0,0,0,0};

  const int srow0 = t >> 3, sc = t & 7, srow1 = (t >> 3) + 32;
  short8v stk0, stk1, stv0, stv1;

  for (int jt = 0; jt < 32; ++jt) {
    const int j0 = jt * 64;
    const bool have_next = (jt < 31);

    // v(jt) from regs -> LDS (post-B2(jt-1); all PV reads of v(jt-1) done)
    if (jt > 0) {
      *(short8v*)&vt_lds[srow0*64 + ((sc ^ (srow0 & 7))*8)] = stv0;
      *(short8v*)&vt_lds[srow1*64 + ((sc ^ (srow1 & 7))*8)] = stv1;
    }
    if (have_next) {                 // issue next-tile global loads
      const int j0n = j0 + 64;
      stk0 = *(const short8v*)&kb[(size_t)(j0n + srow0)*64 + sc*8];
      stk1 = *(const short8v*)&kb[(size_t)(j0n + srow1)*64 + sc*8];
      stv0 = *(const short8v*)&vtb[(size_t)srow0*2048 + j0n + sc*8];
      stv1 = *(const short8v*)&vtb[(size_t)srow1*2048 + j0n + sc*8];
    }

    // --- QK^T: 2 C-tiles (n=0,1), K=64 in 2 steps ---
    f32x4 c0 = {0,0,0,0}, c1 = {0,0,0,0};
    {
      const int jr0 = jh*32 + lrow, jr1 = jh*32 + 16 + lrow;
      const short8v b00 = *(const short8v*)&k_lds[jr0*64 + ((g*8) ^ swz)];
      const short8v b01 = *(const short8v*)&k_lds[jr0*64 + ((32 + g*8) ^ swz)];
      const short8v b10 = *(const short8v*)&k_lds[jr1*64 + ((g*8) ^ swz)];
      const short8v b11 = *(const short8v*)&k_lds[jr1*64 + ((32 + g*8) ^ swz)];
      c0 = MFMA16x16x32(aq0, b00, c0);
      c0 = MFMA16x16x32(aq1, b01, c0);
      c1 = MFMA16x16x32(aq0, b10, c1);
      c1 = MFMA16x16x32(aq1, b11, c1);
    }

    const float m0v = (1.0f - mb[j0 + jh*32 + lrow])      * -10000.0f;
    const float m1v = (1.0f - mb[j0 + jh*32 + 16 + lrow]) * -10000.0f;

    if (j0 <= i0 - 192) {            // whole tile -> bucket 0
      #pragma unroll
      for (int r = 0; r < 4; ++r) {
        const int il  = ih*16 + 4*g + r;
        const int wsw = ((4*g + r) & 7) << 3;
        const float p0 = __expf(c0[r]*0.125f + rs_lo[r] + m0v - 8.0f);
        const float p1 = __expf(c1[r]*0.125f + rs_lo[r] + m1v - 8.0f);
        qp_lds[il*64 + ((jh*32 + lrow) ^ wsw)]      = f2bf(p0);
        qp_lds[il*64 + ((jh*32 + 16 + lrow) ^ wsw)] = f2bf(p1);
        rpl_p[r] += p0 + p1; ls_p[r] += p0 + p1;
      }
    } else if (j0 >= i0 + 159) {     // whole tile -> bucket 255
      #pragma unroll
      for (int r = 0; r < 4; ++r) {
        const int il  = ih*16 + 4*g + r;
        const int wsw = ((4*g + r) & 7) << 3;
        const float p0 = __expf(c0[r]*0.125f + rs_hi[r] + m0v - 8.0f);
        const float p1 = __expf(c1[r]*0.125f + rs_hi[r] + m1v - 8.0f);
        qp_lds[il*64 + ((jh*32 + lrow) ^ wsw)]      = f2bf(p0);
        qp_lds[il*64 + ((jh*32 + 16 + lrow) ^ wsw)] = f2bf(p1);
        rph_p[r] += p0 + p1; ls_p[r] += p0 + p1;
      }
    } else {                         // band: per-element bucket
      #pragma unroll
      for (int r = 0; r < 4; ++r) {
        const int il  = ih*16 + 4*g + r;
        const int gi  = i0 + il;
        const int wsw = ((4*g + r) & 7) << 3;
        {
          const int jl = jh*32 + lrow, gj = j0 + jl;
          int rel = gj - gi; rel = rel < -128 ? -128 : (rel > 127 ? 127 : rel);
          const int bk = rel + 128;
          const float p = __expf(c0[r]*0.125f + rsb[il*256 + bk] + m0v - 8.0f);
          qp_lds[il*64 + (jl ^ wsw)] = f2bf(p);
          if (bk == 0)        rpl_p[r] += p;
          else if (bk == 255) rph_p[r] += p;
          else rp_bf[il*256 + (((bk >> 3) ^ (il & 7)) << 3) + (bk & 7)] = f2bf(p);
          ls_p[r] += p;
        }
        {
          const int jl = jh*32 + 16 + lrow, gj = j0 + jl;
          int rel = gj - gi; rel = rel < -128 ? -128 : (rel > 127 ? 127 : rel);
          const int bk = rel + 128;
          const float p = __expf(c1[r]*0.125f + rsb[il*256 + bk] + m1v - 8.0f);
          qp_lds[il*64 + (jl ^ wsw)] = f2bf(p);
          if (bk == 0)        rpl_p[r] += p;
          else if (bk == 255) rph_p[r] += p;
          else rp_bf[il*256 + (((bk >> 3) ^ (il & 7)) << 3) + (bk & 7)] = f2bf(p);
          ls_p[r] += p;
        }
      }
    }
    __syncthreads();                 // B1: p visible; all k(jt) reads done

    // k(jt+1) from regs -> LDS (k(jt) dead)
    if (have_next) {
      *(short8v*)&k_lds[srow0*64 + ((sc ^ (srow0 & 7))*8)] = stk0;
      *(short8v*)&k_lds[srow1*64 + ((sc ^ (srow1 & 7))*8)] = stk1;
    }

    // --- PV: ctx[i][d] += P[i][:] @ V[:, d] ---
    {
      const int prow = ih*16 + lrow;
      const short8v pa0 = *(const short8v*)&qp_lds[prow*64 + ((g*8) ^ swz)];
      const short8v pa1 = *(const short8v*)&qp_lds[prow*64 + ((32 + g*8) ^ swz)];
      const int d0 = jh*32 + lrow, d1 = jh*32 + 16 + lrow;
      const short8v vb00 = *(const short8v*)&vt_lds[d0*64 + ((g*8) ^ swz)];
      const short8v vb01 = *(const short8v*)&vt_lds[d0*64 + ((32 + g*8) ^ swz)];
      const short8v vb10 = *(const short8v*)&vt_lds[d1*64 + ((g*8) ^ swz)];
      const short8v vb11 = *(const short8v*)&vt_lds[d1*64 + ((32 + g*8) ^ swz)];
      ctx0 = MFMA16x16x32(pa0, vb00, ctx0);
      ctx0 = MFMA16x16x32(pa1, vb01, ctx0);
      ctx1 = MFMA16x16x32(pa0, vb10, ctx1);
      ctx1 = MFMA16x16x32(pa1, vb11, ctx1);
    }
    __syncthreads();                 // B2: PV reads done; k(jt+1) visible
  }

  // --- fold per-lane partials (edges + row sums), once ---
  #pragma unroll
  for (int r = 0; r < 4; ++r) {
    float a = ls_p[r], bl = rpl_p[r], bhv = rph_p[r];
    #pragma unroll
    for (int m = 1; m < 16; m <<= 1) {
      a   += __shfl_xor(a, m);
      bl  += __shfl_xor(bl, m);
      bhv += __shfl_xor(bhv, m);
    }
    if (lrow == 0) {
      const int il = ih*16 + 4*g + r;
      LDS_ATOMIC_ADD(&l_s[il], a);
      LDS_ATOMIC_ADD(&edge_f[2*il + 0], bl);
      LDS_ATOMIC_ADD(&edge_f[2*il + 1], bhv);
    }
  }
  __syncthreads();

  // patch rp_bf edge buckets (swizzled addresses; bk=0 -> chunk 0 elem 0,
  // bk=255 -> chunk 31 elem 7)
  if (t < 32) {
    const int row = t;
    rp_bf[row*256 + (((0  ^ (row & 7))) << 3) + 0] = f2bf(edge_f[2*row + 0]);
    rp_bf[row*256 + (((31 ^ (row & 7))) << 3) + 7] = f2bf(edge_f[2*row + 1]);
  }
  __syncthreads();

  // --- rel-value epilogue: ctx += rp @ rve (K=256) ---
  {
    const int arow = ih*16 + lrow;
    const int d0 = jh*32 + lrow, d1 = jh*32 + 16 + lrow;
    #pragma unroll
    for (int ks = 0; ks < 8; ++ks) {
      const short8v a  = *(const short8v*)&rp_bf[arow*256 + (((ks*4 + g) ^ (lrow & 7))*8)];
      const short8v b0 = *(const short8v*)&rvet[d0*256 + ks*32 + g*8];
      const short8v b1 = *(const short8v*)&rvet[d1*256 + ks*32 + g*8];
      ctx0 = MFMA16x16x32(a, b0, ctx0);
      ctx1 = MFMA16x16x32(a, b1, ctx1);
    }
  }

  // --- normalize + store ---
  #pragma unroll
  for (int r = 0; r < 4; ++r) {
    const int il = ih*16 + 4*g + r;
    const float invl = 1.0f / l_s[il];
    const int gi = i0 + il;
    out[(size_t)(b*2048 + gi)*768 + h*64 + jh*32 + lrow]      = ctx0[r] * invl;
    out[(size_t)(b*2048 + gi)*768 + h*64 + jh*32 + 16 + lrow] = ctx1[r] * invl;
  }
}

// ---------------- launcher ----------------
extern "C" void kernel_launch(void* const* d_in, const int* in_sizes, int n_in,
                              void* d_out, int out_size, void* d_ws, size_t ws_size,
                              hipStream_t stream) {
  const float* hs   = (const float*)d_in[0];
  const float* mask = (const float*)d_in[1];
  const float* Wq   = (const float*)d_in[2];
  const float* bq   = (const float*)d_in[3];
  const float* Wk   = (const float*)d_in[4];
  const float* bk   = (const float*)d_in[5];
  const float* Wv   = (const float*)d_in[6];
  const float* bv   = (const float*)d_in[7];
  const float* rke  = (const float*)d_in[8];
  const float* rve  = (const float*)d_in[9];
  // d_in[10] = indices, recomputed analytically on device.

  const size_t need_bytes = 72810496;
  if (ws_size < need_bytes) return;

  short* p     = (short*)d_ws;
  float* rsw   = (float*)d_ws;            // 12,582,912 f32 (aliases hs splits)
  short* hs_hi = p;                       // 3,145,728
  short* hs_lo = p + 3145728;
  short* wtb   = p + 25165824;            // 1,769,472
  short* qbf   = p + 26935296;            // 3,145,728
  short* kbf   = p + 30081024;
  short* vtbf  = p + 33226752;
  short* rvet  = p + 36372480;            // 16,384
  short* rkeb  = p + 36388864;            // 16,384
  float* out   = (float*)d_out;

  prep_hs_kernel<<<dim3(1536), dim3(256), 0, stream>>>(hs, hs_hi, hs_lo);
  prep_wt_kernel<<<dim3(12, 12, 3), dim3(256), 0, stream>>>(Wq, Wk, Wv, wtb);
  rvet_kernel<<<dim3(1), dim3(256), 0, stream>>>(rve, rke, rvet, rkeb);
  qkv_mfma_kernel<<<dim3(32, 6, 3), dim3(256), 0, stream>>>(
      hs_hi, hs_lo, wtb, bq, bk, bv, qbf, kbf, vtbf);
  rel_scores_mfma_kernel<<<dim3(192, 4), dim3(256), 0, stream>>>(qbf, rkeb, rsw);
  attn_mfma_kernel<<<dim3(64, 24), dim3(256), 0, stream>>>(
      qbf, kbf, vtbf, rsw, rvet, mask, out);
}

// Round 8
// 262.935 us; speedup vs baseline: 5.0082x; 1.1010x over previous
//
#include <hip/hip_runtime.h>
#include <hip/hip_bf16.h>
#include <math.h>

// Problem constants: B=2, S=2048, H=768, NH=12, D=64, R=256, MAX_REL=128
// BH = 24; QKV GEMM rows M = 4096.

#define LDS_ATOMIC_ADD(p, v) __hip_atomic_fetch_add((p), (v), __ATOMIC_RELAXED, __HIP_MEMORY_SCOPE_WORKGROUP)

typedef short short8v __attribute__((ext_vector_type(8)));
typedef short short4v __attribute__((ext_vector_type(4)));
typedef float f32x4 __attribute__((ext_vector_type(4)));

#define MFMA16x16x32(a, b, c) __builtin_amdgcn_mfma_f32_16x16x32_bf16((a), (b), (c), 0, 0, 0)

// float -> bf16 bits, round-to-nearest-even (values are finite here)
__device__ inline short f2bf(float f) {
  unsigned u = __float_as_uint(f);
  unsigned r = (u + 0x7FFFu + ((u >> 16) & 1u)) >> 16;
  return (short)r;
}
__device__ inline float bf2f(short b) {
  return __uint_as_float(((unsigned)(unsigned short)b) << 16);
}

// ---------------- Prep A: hs -> (hi, lo) bf16 split ----------------
__global__ __launch_bounds__(256) void prep_hs_kernel(
    const float* __restrict__ hs, short* __restrict__ hi, short* __restrict__ lo) {
  const size_t base = ((size_t)blockIdx.x * 256 + threadIdx.x) * 8;
  const float4 a = *(const float4*)&hs[base];
  const float4 b = *(const float4*)&hs[base + 4];
  float x[8] = {a.x, a.y, a.z, a.w, b.x, b.y, b.z, b.w};
  short8v h, l;
  #pragma unroll
  for (int i = 0; i < 8; ++i) {
    h[i] = f2bf(x[i]);
    l[i] = f2bf(x[i] - bf2f(h[i]));
  }
  *(short8v*)&hi[base] = h;
  *(short8v*)&lo[base] = l;
}

// ---------------- Prep B: W [768k][768n] -> WT bf16 [w][768n][768k] ----------------
__global__ __launch_bounds__(256) void prep_wt_kernel(
    const float* __restrict__ Wq, const float* __restrict__ Wk,
    const float* __restrict__ Wv, short* __restrict__ wt) {
  __shared__ float tile[64][65];
  const int t = threadIdx.x, tx = t & 15, ty = t >> 4;
  const int w = blockIdx.z;
  const float* W = (w == 0) ? Wq : (w == 1) ? Wk : Wv;
  const int k0 = blockIdx.x * 64, n0 = blockIdx.y * 64;
  #pragma unroll
  for (int rr = 0; rr < 4; ++rr) {
    const int kr = rr * 16 + ty;
    const float4 v = *(const float4*)&W[(size_t)(k0 + kr) * 768 + n0 + tx * 4];
    tile[kr][tx*4 + 0] = v.x; tile[kr][tx*4 + 1] = v.y;
    tile[kr][tx*4 + 2] = v.z; tile[kr][tx*4 + 3] = v.w;
  }
  __syncthreads();
  #pragma unroll
  for (int rr = 0; rr < 4; ++rr) {
    const int nr = rr * 16 + ty;
    short4v s;
    #pragma unroll
    for (int c = 0; c < 4; ++c) s[c] = f2bf(tile[tx*4 + c][nr]);
    *(short4v*)&wt[((size_t)w * 768 + n0 + nr) * 768 + k0 + tx * 4] = s;
  }
}

// ---------------- Prep C: rvet = rve^T bf16 [64][256]; rkeb = rke bf16 ----------------
// grid (64): one element per thread.
__global__ __launch_bounds__(256) void rvet_kernel(
    const float* __restrict__ rve, const float* __restrict__ rke,
    short* __restrict__ rvet, short* __restrict__ rkeb) {
  const int idx = blockIdx.x * 256 + threadIdx.x;   // 0..16383
  const int r = idx >> 6, d = idx & 63;
  rvet[d*256 + r] = f2bf(rve[idx]);
  rkeb[idx]       = f2bf(rke[idx]);
}

// ---------------- Kernel 1: QKV projection, MFMA bf16x2 ----------------
// All three outputs stored in [bh][s][64] layout (coalesced 32B runs);
// V is transposed to [bh][d][s] by transpose_v_kernel afterwards.
__global__ __launch_bounds__(256) void qkv_mfma_kernel(
    const short* __restrict__ hs_hi, const short* __restrict__ hs_lo,
    const short* __restrict__ wt,
    const float* __restrict__ bq, const float* __restrict__ bk,
    const float* __restrict__ bv,
    short* __restrict__ qbf, short* __restrict__ kbf, short* __restrict__ vbf) {
  __shared__ short lds[3 * 8192];
  short* Ah = lds;                 // [128][64] swizzled
  short* Al = lds + 8192;
  short* Bt = lds + 16384;         // [128 n-rows][64 k]

  const int t = threadIdx.x, lane = t & 63, wv = t >> 6;
  const int wm = wv & 1, wn = wv >> 1;
  const int lrow = lane & 15, g = lane >> 4;
  const int m0 = blockIdx.x * 128, n0 = blockIdx.y * 128, w = blockIdx.z;
  const short* Bg = wt + (size_t)w * 768 * 768;
  const float* bias = (w == 0) ? bq : (w == 1) ? bk : bv;
  short* outp = (w == 0) ? qbf : (w == 1) ? kbf : vbf;

  int srow[4], sc[4];
  #pragma unroll
  for (int e = 0; e < 4; ++e) {
    const int id = t + 256*e;
    srow[e] = id >> 3; sc[e] = id & 7;
  }

  #pragma unroll
  for (int e = 0; e < 4; ++e) {
    const int row = srow[e], c = sc[e];
    const int dst = row*64 + ((c ^ (row & 7)) * 8);
    *(short8v*)&Ah[dst] = *(const short8v*)&hs_hi[(size_t)(m0 + row)*768 + c*8];
    *(short8v*)&Al[dst] = *(const short8v*)&hs_lo[(size_t)(m0 + row)*768 + c*8];
    *(short8v*)&Bt[dst] = *(const short8v*)&Bg[(size_t)(n0 + row)*768 + c*8];
  }
  __syncthreads();

  f32x4 acc[4][4] = {};

  for (int kt = 0; kt < 12; ++kt) {
    short8v pa[4], pl[4], pb[4];
    const bool have_next = (kt < 11);
    if (have_next) {
      const int k0n = (kt + 1) * 64;
      #pragma unroll
      for (int e = 0; e < 4; ++e) {
        const int row = srow[e], c = sc[e];
        pa[e] = *(const short8v*)&hs_hi[(size_t)(m0 + row)*768 + k0n + c*8];
        pl[e] = *(const short8v*)&hs_lo[(size_t)(m0 + row)*768 + k0n + c*8];
        pb[e] = *(const short8v*)&Bg   [(size_t)(n0 + row)*768 + k0n + c*8];
      }
    }

    #pragma unroll
    for (int kc = 0; kc < 2; ++kc) {
      short8v af[4], alf[4], bfv[4];
      #pragma unroll
      for (int fm = 0; fm < 4; ++fm) {
        const int row = wm*64 + fm*16 + lrow;
        const int off = row*64 + (((kc*4 + g) ^ (row & 7)) * 8);
        af[fm]  = *(const short8v*)&Ah[off];
        alf[fm] = *(const short8v*)&Al[off];
      }
      #pragma unroll
      for (int fn = 0; fn < 4; ++fn) {
        const int row = wn*64 + fn*16 + lrow;
        bfv[fn] = *(const short8v*)&Bt[row*64 + (((kc*4 + g) ^ (row & 7)) * 8)];
      }
      #pragma unroll
      for (int fm = 0; fm < 4; ++fm)
        #pragma unroll
        for (int fn = 0; fn < 4; ++fn) {
          acc[fm][fn] = MFMA16x16x32(af[fm],  bfv[fn], acc[fm][fn]);
          acc[fm][fn] = MFMA16x16x32(alf[fm], bfv[fn], acc[fm][fn]);
        }
    }
    __syncthreads();
    if (have_next) {
      #pragma unroll
      for (int e = 0; e < 4; ++e) {
        const int row = srow[e], c = sc[e];
        const int dst = row*64 + ((c ^ (row & 7)) * 8);
        *(short8v*)&Ah[dst] = pa[e];
        *(short8v*)&Al[dst] = pl[e];
        *(short8v*)&Bt[dst] = pb[e];
      }
    }
    __syncthreads();
  }

  float bias_v[4];
  #pragma unroll
  for (int fn = 0; fn < 4; ++fn) bias_v[fn] = bias[n0 + wn*64 + fn*16 + lrow];

  #pragma unroll
  for (int fm = 0; fm < 4; ++fm) {
    #pragma unroll
    for (int r = 0; r < 4; ++r) {
      const int m = m0 + wm*64 + fm*16 + g*4 + r;
      const int b = m >> 11, s = m & 2047;
      #pragma unroll
      for (int fn = 0; fn < 4; ++fn) {
        const int n = n0 + wn*64 + fn*16 + lrow;
        const int h = n >> 6, d = n & 63;
        const size_t bh = (size_t)b*12 + h;
        outp[(bh*2048 + s)*64 + d] = f2bf(acc[fm][fn][r] + bias_v[fn]);
      }
    }
  }
}

// ---------------- Kernel 1b: V transpose [bh][s][64] -> [bh][d][2048] ----------------
// grid (32, 24); 64x64 bf16 LDS tile, both global sides coalesced.
__global__ __launch_bounds__(256) void transpose_v_kernel(
    const short* __restrict__ vbf, short* __restrict__ vtbf) {
  __shared__ short tile[64][66];
  const int t = threadIdx.x;
  const int bh = blockIdx.y;
  const int s0 = blockIdx.x * 64;
  const short* src = vbf + ((size_t)bh*2048 + s0)*64;
  const int row = t >> 3, c = t & 7;   // row 0..31, c 0..7
  #pragma unroll
  for (int e = 0; e < 2; ++e) {
    const int r = row + 32*e;
    *(short8v*)&tile[r][c*8] = *(const short8v*)&src[(size_t)r*64 + c*8];
  }
  __syncthreads();
  #pragma unroll
  for (int e = 0; e < 2; ++e) {
    const int d = row + 32*e;
    short8v v;
    #pragma unroll
    for (int k = 0; k < 8; ++k) v[k] = tile[c*8 + k][d];
    *(short8v*)&vtbf[((size_t)bh*64 + d)*2048 + s0 + c*8] = v;
  }
}

// ---------------- Kernel 2: rel_scores (MFMA) -> bf16 output ----------------
__global__ __launch_bounds__(256) void rel_scores_mfma_kernel(
    const short* __restrict__ qbf, const short* __restrict__ rkeb,
    short* __restrict__ rs) {
  __shared__ short Atile[256 * 64];   // 32 KB swizzled
  __shared__ short Btile[64 * 64];    //  8 KB swizzled
  const int t = threadIdx.x, lane = t & 63, wv = t >> 6;
  const int lrow = lane & 15, g = lane >> 4;
  const int m0 = blockIdx.x * 256, n0 = blockIdx.y * 64;

  #pragma unroll
  for (int e = 0; e < 8; ++e) {
    const int id = t + 256*e, row = id >> 3, c = id & 7;
    *(short8v*)&Atile[row*64 + ((c ^ (row & 7)) * 8)] =
        *(const short8v*)&qbf[(size_t)(m0 + row)*64 + c*8];
  }
  #pragma unroll
  for (int e = 0; e < 2; ++e) {
    const int id = t + 256*e, row = id >> 3, c = id & 7;
    *(short8v*)&Btile[row*64 + ((c ^ (row & 7)) * 8)] =
        *(const short8v*)&rkeb[(size_t)(n0 + row)*64 + c*8];
  }
  __syncthreads();

  f32x4 acc[4][4] = {};
  #pragma unroll
  for (int kc = 0; kc < 2; ++kc) {
    short8v af[4], bfv[4];
    #pragma unroll
    for (int fm = 0; fm < 4; ++fm) {
      const int row = wv*64 + fm*16 + lrow;
      af[fm] = *(const short8v*)&Atile[row*64 + (((kc*4 + g) ^ (row & 7)) * 8)];
    }
    #pragma unroll
    for (int fn = 0; fn < 4; ++fn) {
      const int row = fn*16 + lrow;
      bfv[fn] = *(const short8v*)&Btile[row*64 + (((kc*4 + g) ^ (row & 7)) * 8)];
    }
    #pragma unroll
    for (int fm = 0; fm < 4; ++fm)
      #pragma unroll
      for (int fn = 0; fn < 4; ++fn)
        acc[fm][fn] = MFMA16x16x32(af[fm], bfv[fn], acc[fm][fn]);
  }

  #pragma unroll
  for (int fm = 0; fm < 4; ++fm)
    #pragma unroll
    for (int r = 0; r < 4; ++r) {
      const int m = m0 + wv*64 + fm*16 + g*4 + r;
      #pragma unroll
      for (int fn = 0; fn < 4; ++fn)
        rs[(size_t)m*256 + n0 + fn*16 + lrow] = f2bf(acc[fm][fn][r] * 0.125f);
    }
}

// ---------------- Kernel 3: fused attention, MFMA bf16 ----------------
// Same verified structure as round 6; rs is bf16.
__global__ __launch_bounds__(256) void attn_mfma_kernel(
    const short* __restrict__ qbf, const short* __restrict__ kbf,
    const short* __restrict__ vtbf, const short* __restrict__ rs,
    const short* __restrict__ rvet, const float* __restrict__ mask,
    float* __restrict__ out) {
  __shared__ __align__(16) char smem[37248];
  short* rp_bf  = (short*)smem;                 // [32*256] bf16, swizzled  16384 B
  short* k_lds  = (short*)(smem + 16384);       // [64*64]                   8192 B
  short* vt_lds = (short*)(smem + 24576);       // [64*64]                   8192 B
  short* qp_lds = (short*)(smem + 32768);       // [32*64] q, then p         4096 B
  float* l_s    = (float*)(smem + 36864);       // [32]                       128 B
  float* edge_f = (float*)(smem + 36992);       // [32][2]                    256 B

  const int t    = threadIdx.x;
  const int lane = t & 63, wv = t >> 6;
  const int ih   = wv & 1, jh = wv >> 1;
  const int lrow = lane & 15, g = lane >> 4;
  const int swz  = (lrow & 7) << 3;

  const int bh = blockIdx.y, b = bh / 12, h = bh % 12;
  const int i0 = blockIdx.x * 32;

  const short* qb  = qbf  + ((size_t)bh*2048 + i0)*64;
  const short* kb  = kbf  + (size_t)bh*2048*64;
  const short* vtb = vtbf + (size_t)bh*64*2048;
  const short* rsb = rs   + ((size_t)bh*2048 + i0)*256;
  const float* mb  = mask + (size_t)b*2048;

  // zero rp_bf (16 KB) + l/edge
  {
    const short8v z8 = {0,0,0,0,0,0,0,0};
    #pragma unroll
    for (int e = 0; e < 4; ++e) *(short8v*)&rp_bf[(e*256 + t)*8] = z8;
    if (t < 32) { l_s[t] = 0.f; edge_f[2*t] = 0.f; edge_f[2*t+1] = 0.f; }
  }
  // stage q (32 rows x 8 chunks)
  {
    const int row = t >> 3, c = t & 7;
    *(short8v*)&qp_lds[row*64 + ((c ^ (row & 7))*8)] =
        *(const short8v*)&qb[row*64 + c*8];
  }
  // stage k/vt tile 0 (single buffers)
  #pragma unroll
  for (int e = 0; e < 2; ++e) {
    const int id = t + 256*e, row = id >> 3, c = id & 7;
    *(short8v*)&k_lds[row*64 + ((c ^ (row & 7))*8)] =
        *(const short8v*)&kb[(size_t)row*64 + c*8];
    *(short8v*)&vt_lds[row*64 + ((c ^ (row & 7))*8)] =
        *(const short8v*)&vtb[(size_t)row*2048 + c*8];
  }
  __syncthreads();                       // P1: staging visible

  // hoisted Q A-fragments (loop-invariant)
  const short8v aq0 = *(const short8v*)&qp_lds[(ih*16 + lrow)*64 + ((g*8) ^ swz)];
  const short8v aq1 = *(const short8v*)&qp_lds[(ih*16 + lrow)*64 + ((32 + g*8) ^ swz)];
  __syncthreads();                       // P2: q reads done; p may overwrite

  float rs_lo[4], rs_hi[4];
  #pragma unroll
  for (int r = 0; r < 4; ++r) {
    const int il = ih*16 + 4*g + r;
    rs_lo[r] = bf2f(rsb[il*256 + 0]);
    rs_hi[r] = bf2f(rsb[il*256 + 255]);
  }
  float ls_p[4]  = {0,0,0,0};
  float rpl_p[4] = {0,0,0,0};
  float rph_p[4] = {0,0,0,0};
  f32x4 ctx0 = {0,0,0,0}, ctx1 = {0,0,0,0};

  const int srow0 = t >> 3, sc = t & 7, srow1 = (t >> 3) + 32;
  short8v stk0, stk1, stv0, stv1;

  for (int jt = 0; jt < 32; ++jt) {
    const int j0 = jt * 64;
    const bool have_next = (jt < 31);

    // v(jt) from regs -> LDS (post-B2(jt-1); all PV reads of v(jt-1) done)
    if (jt > 0) {
      *(short8v*)&vt_lds[srow0*64 + ((sc ^ (srow0 & 7))*8)] = stv0;
      *(short8v*)&vt_lds[srow1*64 + ((sc ^ (srow1 & 7))*8)] = stv1;
    }
    if (have_next) {                 // issue next-tile global loads
      const int j0n = j0 + 64;
      stk0 = *(const short8v*)&kb[(size_t)(j0n + srow0)*64 + sc*8];
      stk1 = *(const short8v*)&kb[(size_t)(j0n + srow1)*64 + sc*8];
      stv0 = *(const short8v*)&vtb[(size_t)srow0*2048 + j0n + sc*8];
      stv1 = *(const short8v*)&vtb[(size_t)srow1*2048 + j0n + sc*8];
    }

    // --- QK^T: 2 C-tiles (n=0,1), K=64 in 2 steps ---
    f32x4 c0 = {0,0,0,0}, c1 = {0,0,0,0};
    {
      const int jr0 = jh*32 + lrow, jr1 = jh*32 + 16 + lrow;
      const short8v b00 = *(const short8v*)&k_lds[jr0*64 + ((g*8) ^ swz)];
      const short8v b01 = *(const short8v*)&k_lds[jr0*64 + ((32 + g*8) ^ swz)];
      const short8v b10 = *(const short8v*)&k_lds[jr1*64 + ((g*8) ^ swz)];
      const short8v b11 = *(const short8v*)&k_lds[jr1*64 + ((32 + g*8) ^ swz)];
      c0 = MFMA16x16x32(aq0, b00, c0);
      c0 = MFMA16x16x32(aq1, b01, c0);
      c1 = MFMA16x16x32(aq0, b10, c1);
      c1 = MFMA16x16x32(aq1, b11, c1);
    }

    const float m0v = (1.0f - mb[j0 + jh*32 + lrow])      * -10000.0f;
    const float m1v = (1.0f - mb[j0 + jh*32 + 16 + lrow]) * -10000.0f;

    if (j0 <= i0 - 192) {            // whole tile -> bucket 0
      #pragma unroll
      for (int r = 0; r < 4; ++r) {
        const int il  = ih*16 + 4*g + r;
        const int wsw = ((4*g + r) & 7) << 3;
        const float p0 = __expf(c0[r]*0.125f + rs_lo[r] + m0v - 8.0f);
        const float p1 = __expf(c1[r]*0.125f + rs_lo[r] + m1v - 8.0f);
        qp_lds[il*64 + ((jh*32 + lrow) ^ wsw)]      = f2bf(p0);
        qp_lds[il*64 + ((jh*32 + 16 + lrow) ^ wsw)] = f2bf(p1);
        rpl_p[r] += p0 + p1; ls_p[r] += p0 + p1;
      }
    } else if (j0 >= i0 + 159) {     // whole tile -> bucket 255
      #pragma unroll
      for (int r = 0; r < 4; ++r) {
        const int il  = ih*16 + 4*g + r;
        const int wsw = ((4*g + r) & 7) << 3;
        const float p0 = __expf(c0[r]*0.125f + rs_hi[r] + m0v - 8.0f);
        const float p1 = __expf(c1[r]*0.125f + rs_hi[r] + m1v - 8.0f);
        qp_lds[il*64 + ((jh*32 + lrow) ^ wsw)]      = f2bf(p0);
        qp_lds[il*64 + ((jh*32 + 16 + lrow) ^ wsw)] = f2bf(p1);
        rph_p[r] += p0 + p1; ls_p[r] += p0 + p1;
      }
    } else {                         // band: per-element bucket
      #pragma unroll
      for (int r = 0; r < 4; ++r) {
        const int il  = ih*16 + 4*g + r;
        const int gi  = i0 + il;
        const int wsw = ((4*g + r) & 7) << 3;
        {
          const int jl = jh*32 + lrow, gj = j0 + jl;
          int rel = gj - gi; rel = rel < -128 ? -128 : (rel > 127 ? 127 : rel);
          const int bk = rel + 128;
          const float p = __expf(c0[r]*0.125f + bf2f(rsb[il*256 + bk]) + m0v - 8.0f);
          qp_lds[il*64 + (jl ^ wsw)] = f2bf(p);
          if (bk == 0)        rpl_p[r] += p;
          else if (bk == 255) rph_p[r] += p;
          else rp_bf[il*256 + (((bk >> 3) ^ (il & 7)) << 3) + (bk & 7)] = f2bf(p);
          ls_p[r] += p;
        }
        {
          const int jl = jh*32 + 16 + lrow, gj = j0 + jl;
          int rel = gj - gi; rel = rel < -128 ? -128 : (rel > 127 ? 127 : rel);
          const int bk = rel + 128;
          const float p = __expf(c1[r]*0.125f + bf2f(rsb[il*256 + bk]) + m1v - 8.0f);
          qp_lds[il*64 + (jl ^ wsw)] = f2bf(p);
          if (bk == 0)        rpl_p[r] += p;
          else if (bk == 255) rph_p[r] += p;
          else rp_bf[il*256 + (((bk >> 3) ^ (il & 7)) << 3) + (bk & 7)] = f2bf(p);
          ls_p[r] += p;
        }
      }
    }
    __syncthreads();                 // B1: p visible; all k(jt) reads done

    // k(jt+1) from regs -> LDS (k(jt) dead)
    if (have_next) {
      *(short8v*)&k_lds[srow0*64 + ((sc ^ (srow0 & 7))*8)] = stk0;
      *(short8v*)&k_lds[srow1*64 + ((sc ^ (srow1 & 7))*8)] = stk1;
    }

    // --- PV: ctx[i][d] += P[i][:] @ V[:, d] ---
    {
      const int prow = ih*16 + lrow;
      const short8v pa0 = *(const short8v*)&qp_lds[prow*64 + ((g*8) ^ swz)];
      const short8v pa1 = *(const short8v*)&qp_lds[prow*64 + ((32 + g*8) ^ swz)];
      const int d0 = jh*32 + lrow, d1 = jh*32 + 16 + lrow;
      const short8v vb00 = *(const short8v*)&vt_lds[d0*64 + ((g*8) ^ swz)];
      const short8v vb01 = *(const short8v*)&vt_lds[d0*64 + ((32 + g*8) ^ swz)];
      const short8v vb10 = *(const short8v*)&vt_lds[d1*64 + ((g*8) ^ swz)];
      const short8v vb11 = *(const short8v*)&vt_lds[d1*64 + ((32 + g*8) ^ swz)];
      ctx0 = MFMA16x16x32(pa0, vb00, ctx0);
      ctx0 = MFMA16x16x32(pa1, vb01, ctx0);
      ctx1 = MFMA16x16x32(pa0, vb10, ctx1);
      ctx1 = MFMA16x16x32(pa1, vb11, ctx1);
    }
    __syncthreads();                 // B2: PV reads done; k(jt+1) visible
  }

  // --- fold per-lane partials (edges + row sums), once ---
  #pragma unroll
  for (int r = 0; r < 4; ++r) {
    float a = ls_p[r], bl = rpl_p[r], bhv = rph_p[r];
    #pragma unroll
    for (int m = 1; m < 16; m <<= 1) {
      a   += __shfl_xor(a, m);
      bl  += __shfl_xor(bl, m);
      bhv += __shfl_xor(bhv, m);
    }
    if (lrow == 0) {
      const int il = ih*16 + 4*g + r;
      LDS_ATOMIC_ADD(&l_s[il], a);
      LDS_ATOMIC_ADD(&edge_f[2*il + 0], bl);
      LDS_ATOMIC_ADD(&edge_f[2*il + 1], bhv);
    }
  }
  __syncthreads();

  // patch rp_bf edge buckets
  if (t < 32) {
    const int row = t;
    rp_bf[row*256 + (((0  ^ (row & 7))) << 3) + 0] = f2bf(edge_f[2*row + 0]);
    rp_bf[row*256 + (((31 ^ (row & 7))) << 3) + 7] = f2bf(edge_f[2*row + 1]);
  }
  __syncthreads();

  // --- rel-value epilogue: ctx += rp @ rve (K=256) ---
  {
    const int arow = ih*16 + lrow;
    const int d0 = jh*32 + lrow, d1 = jh*32 + 16 + lrow;
    #pragma unroll
    for (int ks = 0; ks < 8; ++ks) {
      const short8v a  = *(const short8v*)&rp_bf[arow*256 + (((ks*4 + g) ^ (lrow & 7))*8)];
      const short8v b0 = *(const short8v*)&rvet[d0*256 + ks*32 + g*8];
      const short8v b1 = *(const short8v*)&rvet[d1*256 + ks*32 + g*8];
      ctx0 = MFMA16x16x32(a, b0, ctx0);
      ctx1 = MFMA16x16x32(a, b1, ctx1);
    }
  }

  // --- normalize + store ---
  #pragma unroll
  for (int r = 0; r < 4; ++r) {
    const int il = ih*16 + 4*g + r;
    const float invl = 1.0f / l_s[il];
    const int gi = i0 + il;
    out[(size_t)(b*2048 + gi)*768 + h*64 + jh*32 + lrow]      = ctx0[r] * invl;
    out[(size_t)(b*2048 + gi)*768 + h*64 + jh*32 + 16 + lrow] = ctx1[r] * invl;
  }
}

// ---------------- launcher ----------------
extern "C" void kernel_launch(void* const* d_in, const int* in_sizes, int n_in,
                              void* d_out, int out_size, void* d_ws, size_t ws_size,
                              hipStream_t stream) {
  const float* hs   = (const float*)d_in[0];
  const float* mask = (const float*)d_in[1];
  const float* Wq   = (const float*)d_in[2];
  const float* bq   = (const float*)d_in[3];
  const float* Wk   = (const float*)d_in[4];
  const float* bk   = (const float*)d_in[5];
  const float* Wv   = (const float*)d_in[6];
  const float* bv   = (const float*)d_in[7];
  const float* rke  = (const float*)d_in[8];
  const float* rve  = (const float*)d_in[9];
  // d_in[10] = indices, recomputed analytically on device.

  // Workspace (shorts, all disjoint): rs 12.6M | hs_hi/lo 3.1M ea | wt 1.77M |
  // qbf/kbf/vbf/vtbf 3.1M ea | rvet/rkeb 16K ea = 66.5 MB total.
  const size_t need_bytes = 66519040;
  if (ws_size < need_bytes) return;

  short* p     = (short*)d_ws;
  short* rsw   = p;                       // 12,582,912 (bf16)
  short* hs_hi = p + 12582912;            // 3,145,728
  short* hs_lo = p + 15728640;
  short* wtb   = p + 18874368;            // 1,769,472
  short* qbf   = p + 20643840;            // 3,145,728
  short* kbf   = p + 23789568;
  short* vbf   = p + 26935296;
  short* vtbf  = p + 30081024;
  short* rvet  = p + 33226752;            // 16,384
  short* rkeb  = p + 33243136;            // 16,384
  float* out   = (float*)d_out;

  prep_hs_kernel<<<dim3(1536), dim3(256), 0, stream>>>(hs, hs_hi, hs_lo);
  prep_wt_kernel<<<dim3(12, 12, 3), dim3(256), 0, stream>>>(Wq, Wk, Wv, wtb);
  rvet_kernel<<<dim3(64), dim3(256), 0, stream>>>(rve, rke, rvet, rkeb);
  qkv_mfma_kernel<<<dim3(32, 6, 3), dim3(256), 0, stream>>>(
      hs_hi, hs_lo, wtb, bq, bk, bv, qbf, kbf, vbf);
  transpose_v_kernel<<<dim3(32, 24), dim3(256), 0, stream>>>(vbf, vtbf);
  rel_scores_mfma_kernel<<<dim3(192, 4), dim3(256), 0, stream>>>(qbf, rkeb, rsw);
  attn_mfma_kernel<<<dim3(64, 24), dim3(256), 0, stream>>>(
      qbf, kbf, vtbf, rsw, rvet, mask, out);
}

// Round 9
// 245.712 us; speedup vs baseline: 5.3593x; 1.0701x over previous
//
#include <hip/hip_runtime.h>
#include <hip/hip_bf16.h>
#include <math.h>

// Problem constants: B=2, S=2048, H=768, NH=12, D=64, R=256, MAX_REL=128
// BH = 24; QKV GEMM rows M = 4096.

#define LDS_ATOMIC_ADD(p, v) __hip_atomic_fetch_add((p), (v), __ATOMIC_RELAXED, __HIP_MEMORY_SCOPE_WORKGROUP)

typedef short short8v __attribute__((ext_vector_type(8)));
typedef short short4v __attribute__((ext_vector_type(4)));
typedef float f32x4 __attribute__((ext_vector_type(4)));

#define MFMA16x16x32(a, b, c) __builtin_amdgcn_mfma_f32_16x16x32_bf16((a), (b), (c), 0, 0, 0)

// float -> bf16 bits, round-to-nearest-even (values are finite here)
__device__ inline short f2bf(float f) {
  unsigned u = __float_as_uint(f);
  unsigned r = (u + 0x7FFFu + ((u >> 16) & 1u)) >> 16;
  return (short)r;
}
__device__ inline float bf2f(short b) {
  return __uint_as_float(((unsigned)(unsigned short)b) << 16);
}

// ---------------- Prep B: W [768k][768n] -> WT bf16 [w][768n][768k] ----------------
__global__ __launch_bounds__(256) void prep_wt_kernel(
    const float* __restrict__ Wq, const float* __restrict__ Wk,
    const float* __restrict__ Wv, short* __restrict__ wt) {
  __shared__ float tile[64][65];
  const int t = threadIdx.x, tx = t & 15, ty = t >> 4;
  const int w = blockIdx.z;
  const float* W = (w == 0) ? Wq : (w == 1) ? Wk : Wv;
  const int k0 = blockIdx.x * 64, n0 = blockIdx.y * 64;
  #pragma unroll
  for (int rr = 0; rr < 4; ++rr) {
    const int kr = rr * 16 + ty;
    const float4 v = *(const float4*)&W[(size_t)(k0 + kr) * 768 + n0 + tx * 4];
    tile[kr][tx*4 + 0] = v.x; tile[kr][tx*4 + 1] = v.y;
    tile[kr][tx*4 + 2] = v.z; tile[kr][tx*4 + 3] = v.w;
  }
  __syncthreads();
  #pragma unroll
  for (int rr = 0; rr < 4; ++rr) {
    const int nr = rr * 16 + ty;
    short4v s;
    #pragma unroll
    for (int c = 0; c < 4; ++c) s[c] = f2bf(tile[tx*4 + c][nr]);
    *(short4v*)&wt[((size_t)w * 768 + n0 + nr) * 768 + k0 + tx * 4] = s;
  }
}

// ---------------- Prep C: rvet = rve^T bf16 [64][256]; rkeb = rke bf16 ----------------
__global__ __launch_bounds__(256) void rvet_kernel(
    const float* __restrict__ rve, const float* __restrict__ rke,
    short* __restrict__ rvet, short* __restrict__ rkeb) {
  const int idx = blockIdx.x * 256 + threadIdx.x;   // 0..16383
  const int r = idx >> 6, d = idx & 63;
  rvet[d*256 + r] = f2bf(rve[idx]);
  rkeb[idx]       = f2bf(rke[idx]);
}

// ---------------- Kernel 1: QKV projection, MFMA bf16x2 ----------------
// hs read as f32, hi/lo split computed in-register at staging time.
// Outputs in [bh][s][64] layout; V transposed by transpose_v_kernel.
__global__ __launch_bounds__(256) void qkv_mfma_kernel(
    const float* __restrict__ hs, const short* __restrict__ wt,
    const float* __restrict__ bq, const float* __restrict__ bk,
    const float* __restrict__ bv,
    short* __restrict__ qbf, short* __restrict__ kbf, short* __restrict__ vbf) {
  __shared__ short lds[3 * 8192];
  short* Ah = lds;                 // [128][64] swizzled
  short* Al = lds + 8192;
  short* Bt = lds + 16384;         // [128 n-rows][64 k]

  const int t = threadIdx.x, lane = t & 63, wv = t >> 6;
  const int wm = wv & 1, wn = wv >> 1;
  const int lrow = lane & 15, g = lane >> 4;
  const int m0 = blockIdx.x * 128, n0 = blockIdx.y * 128, w = blockIdx.z;
  const short* Bg = wt + (size_t)w * 768 * 768;
  const float* bias = (w == 0) ? bq : (w == 1) ? bk : bv;
  short* outp = (w == 0) ? qbf : (w == 1) ? kbf : vbf;

  int srow[4], sc[4];
  #pragma unroll
  for (int e = 0; e < 4; ++e) {
    const int id = t + 256*e;
    srow[e] = id >> 3; sc[e] = id & 7;
  }

  // prologue: stage K-step 0 (split hs f32 -> hi/lo in-register)
  #pragma unroll
  for (int e = 0; e < 4; ++e) {
    const int row = srow[e], c = sc[e];
    const int dst = row*64 + ((c ^ (row & 7)) * 8);
    const float* s = &hs[(size_t)(m0 + row)*768 + c*8];
    const float4 f0 = *(const float4*)s, f1 = *(const float4*)(s + 4);
    float x[8] = {f0.x, f0.y, f0.z, f0.w, f1.x, f1.y, f1.z, f1.w};
    short8v hiv, lov;
    #pragma unroll
    for (int i = 0; i < 8; ++i) {
      hiv[i] = f2bf(x[i]);
      lov[i] = f2bf(x[i] - bf2f(hiv[i]));
    }
    *(short8v*)&Ah[dst] = hiv;
    *(short8v*)&Al[dst] = lov;
    *(short8v*)&Bt[dst] = *(const short8v*)&Bg[(size_t)(n0 + row)*768 + c*8];
  }
  __syncthreads();

  f32x4 acc[4][4] = {};

  for (int kt = 0; kt < 12; ++kt) {
    float4 pf0[4], pf1[4];
    short8v pb[4];
    const bool have_next = (kt < 11);
    if (have_next) {
      const int k0n = (kt + 1) * 64;
      #pragma unroll
      for (int e = 0; e < 4; ++e) {
        const int row = srow[e], c = sc[e];
        const float* s = &hs[(size_t)(m0 + row)*768 + k0n + c*8];
        pf0[e] = *(const float4*)s;
        pf1[e] = *(const float4*)(s + 4);
        pb[e]  = *(const short8v*)&Bg[(size_t)(n0 + row)*768 + k0n + c*8];
      }
    }

    #pragma unroll
    for (int kc = 0; kc < 2; ++kc) {
      short8v af[4], alf[4], bfv[4];
      #pragma unroll
      for (int fm = 0; fm < 4; ++fm) {
        const int row = wm*64 + fm*16 + lrow;
        const int off = row*64 + (((kc*4 + g) ^ (row & 7)) * 8);
        af[fm]  = *(const short8v*)&Ah[off];
        alf[fm] = *(const short8v*)&Al[off];
      }
      #pragma unroll
      for (int fn = 0; fn < 4; ++fn) {
        const int row = wn*64 + fn*16 + lrow;
        bfv[fn] = *(const short8v*)&Bt[row*64 + (((kc*4 + g) ^ (row & 7)) * 8)];
      }
      #pragma unroll
      for (int fm = 0; fm < 4; ++fm)
        #pragma unroll
        for (int fn = 0; fn < 4; ++fn) {
          acc[fm][fn] = MFMA16x16x32(af[fm],  bfv[fn], acc[fm][fn]);
          acc[fm][fn] = MFMA16x16x32(alf[fm], bfv[fn], acc[fm][fn]);
        }
    }
    __syncthreads();
    if (have_next) {
      #pragma unroll
      for (int e = 0; e < 4; ++e) {
        const int row = srow[e], c = sc[e];
        const int dst = row*64 + ((c ^ (row & 7)) * 8);
        float x[8] = {pf0[e].x, pf0[e].y, pf0[e].z, pf0[e].w,
                      pf1[e].x, pf1[e].y, pf1[e].z, pf1[e].w};
        short8v hiv, lov;
        #pragma unroll
        for (int i = 0; i < 8; ++i) {
          hiv[i] = f2bf(x[i]);
          lov[i] = f2bf(x[i] - bf2f(hiv[i]));
        }
        *(short8v*)&Ah[dst] = hiv;
        *(short8v*)&Al[dst] = lov;
        *(short8v*)&Bt[dst] = pb[e];
      }
    }
    __syncthreads();
  }

  float bias_v[4];
  #pragma unroll
  for (int fn = 0; fn < 4; ++fn) bias_v[fn] = bias[n0 + wn*64 + fn*16 + lrow];

  #pragma unroll
  for (int fm = 0; fm < 4; ++fm) {
    #pragma unroll
    for (int r = 0; r < 4; ++r) {
      const int m = m0 + wm*64 + fm*16 + g*4 + r;
      const int b = m >> 11, s = m & 2047;
      #pragma unroll
      for (int fn = 0; fn < 4; ++fn) {
        const int n = n0 + wn*64 + fn*16 + lrow;
        const int h = n >> 6, d = n & 63;
        const size_t bh = (size_t)b*12 + h;
        outp[(bh*2048 + s)*64 + d] = f2bf(acc[fm][fn][r] + bias_v[fn]);
      }
    }
  }
}

// ---------------- Kernel 1b: V transpose [bh][s][64] -> [bh][d][2048] ----------------
__global__ __launch_bounds__(256) void transpose_v_kernel(
    const short* __restrict__ vbf, short* __restrict__ vtbf) {
  __shared__ short tile[64][66];
  const int t = threadIdx.x;
  const int bh = blockIdx.y;
  const int s0 = blockIdx.x * 64;
  const short* src = vbf + ((size_t)bh*2048 + s0)*64;
  const int row = t >> 3, c = t & 7;   // row 0..31, c 0..7
  #pragma unroll
  for (int e = 0; e < 2; ++e) {
    const int r = row + 32*e;
    *(short8v*)&tile[r][c*8] = *(const short8v*)&src[(size_t)r*64 + c*8];
  }
  __syncthreads();
  #pragma unroll
  for (int e = 0; e < 2; ++e) {
    const int d = row + 32*e;
    short8v v;
    #pragma unroll
    for (int k = 0; k < 8; ++k) v[k] = tile[c*8 + k][d];
    *(short8v*)&vtbf[((size_t)bh*64 + d)*2048 + s0 + c*8] = v;
  }
}

// ---------------- Kernel 3: fused attention + fused rel_scores, MFMA bf16 ----------------
// rel_scores computed in-prologue via MFMA (q from qp_lds, rke from global,
// 16 MFMAs/wave) into rs_lds bf16 (same XOR swizzle as rp_bf). Removes the
// standalone rel_scores kernel and its 50 MB HBM round trip.
// LDS 53.6 KB -> 3 blocks/CU. Main loop identical to round 8.
__global__ __launch_bounds__(256) void attn_mfma_kernel(
    const short* __restrict__ qbf, const short* __restrict__ kbf,
    const short* __restrict__ vtbf, const short* __restrict__ rkeb,
    const short* __restrict__ rvet, const float* __restrict__ mask,
    float* __restrict__ out) {
  __shared__ __align__(16) char smem[53632];
  short* rp_bf   = (short*)smem;                 // [32*256] bf16 swizzled 16384 B
  short* rs_ldsb = (short*)(smem + 16384);       // [32*256] bf16 swizzled 16384 B
  short* k_lds   = (short*)(smem + 32768);       // [64*64]                 8192 B
  short* vt_lds  = (short*)(smem + 40960);       // [64*64]                 8192 B
  short* qp_lds  = (short*)(smem + 49152);       // [32*64] q, then p       4096 B
  float* l_s     = (float*)(smem + 53248);       // [32]                     128 B
  float* edge_f  = (float*)(smem + 53376);       // [32][2]                  256 B

  const int t    = threadIdx.x;
  const int lane = t & 63, wv = t >> 6;
  const int ih   = wv & 1, jh = wv >> 1;
  const int lrow = lane & 15, g = lane >> 4;
  const int swz  = (lrow & 7) << 3;

  const int bh = blockIdx.y, b = bh / 12, h = bh % 12;
  const int i0 = blockIdx.x * 32;

  const short* qb  = qbf  + ((size_t)bh*2048 + i0)*64;
  const short* kb  = kbf  + (size_t)bh*2048*64;
  const short* vtb = vtbf + (size_t)bh*64*2048;
  const float* mb  = mask + (size_t)b*2048;

  // zero rp_bf (16 KB) + l/edge
  {
    const short8v z8 = {0,0,0,0,0,0,0,0};
    #pragma unroll
    for (int e = 0; e < 4; ++e) *(short8v*)&rp_bf[(e*256 + t)*8] = z8;
    if (t < 32) { l_s[t] = 0.f; edge_f[2*t] = 0.f; edge_f[2*t+1] = 0.f; }
  }
  // stage q (32 rows x 8 chunks)
  {
    const int row = t >> 3, c = t & 7;
    *(short8v*)&qp_lds[row*64 + ((c ^ (row & 7))*8)] =
        *(const short8v*)&qb[row*64 + c*8];
  }
  // stage k/vt tile 0 (single buffers)
  #pragma unroll
  for (int e = 0; e < 2; ++e) {
    const int id = t + 256*e, row = id >> 3, c = id & 7;
    *(short8v*)&k_lds[row*64 + ((c ^ (row & 7))*8)] =
        *(const short8v*)&kb[(size_t)row*64 + c*8];
    *(short8v*)&vt_lds[row*64 + ((c ^ (row & 7))*8)] =
        *(const short8v*)&vtb[(size_t)row*2048 + c*8];
  }
  __syncthreads();                       // P1: staging visible

  // hoisted Q A-fragments (loop-invariant)
  const short8v aq0 = *(const short8v*)&qp_lds[(ih*16 + lrow)*64 + ((g*8) ^ swz)];
  const short8v aq1 = *(const short8v*)&qp_lds[(ih*16 + lrow)*64 + ((32 + g*8) ^ swz)];

  // --- fused rel_scores: rs[32][256] = (q @ rke^T)*0.125, bf16 swizzled ---
  // Wave wv owns bucket range wv*64..wv*64+63. B-frags straight from global
  // (rkeb 32 KB, L2-resident). 16 MFMAs/wave. q is still valid in qp_lds.
  {
    f32x4 racc[2][4] = {};
    #pragma unroll
    for (int kc = 0; kc < 2; ++kc) {
      short8v am0 = *(const short8v*)&qp_lds[lrow*64 + (((kc*4 + g) ^ (lrow & 7))*8)];
      short8v am1 = *(const short8v*)&qp_lds[(16 + lrow)*64 + (((kc*4 + g) ^ ((16 + lrow) & 7))*8)];
      #pragma unroll
      for (int fn = 0; fn < 4; ++fn) {
        const short8v bb = *(const short8v*)&rkeb[(size_t)(wv*64 + fn*16 + lrow)*64 + kc*32 + g*8];
        racc[0][fn] = MFMA16x16x32(am0, bb, racc[0][fn]);
        racc[1][fn] = MFMA16x16x32(am1, bb, racc[1][fn]);
      }
    }
    #pragma unroll
    for (int mt = 0; mt < 2; ++mt)
      #pragma unroll
      for (int fn = 0; fn < 4; ++fn)
        #pragma unroll
        for (int r = 0; r < 4; ++r) {
          const int il = mt*16 + 4*g + r;
          const int bk = wv*64 + fn*16 + lrow;
          rs_ldsb[il*256 + (((bk >> 3) ^ (il & 7)) << 3) + (bk & 7)] =
              f2bf(racc[mt][fn][r] * 0.125f);
        }
  }
  __syncthreads();                       // P2: q reads + rs writes done

  float rs_lo[4], rs_hi[4];
  #pragma unroll
  for (int r = 0; r < 4; ++r) {
    const int il = ih*16 + 4*g + r;
    rs_lo[r] = bf2f(rs_ldsb[il*256 + ((il & 7) << 3)]);             // bucket 0
    rs_hi[r] = bf2f(rs_ldsb[il*256 + (((31 ^ (il & 7)) << 3) + 7)]); // bucket 255
  }
  float ls_p[4]  = {0,0,0,0};
  float rpl_p[4] = {0,0,0,0};
  float rph_p[4] = {0,0,0,0};
  f32x4 ctx0 = {0,0,0,0}, ctx1 = {0,0,0,0};

  const int srow0 = t >> 3, sc = t & 7, srow1 = (t >> 3) + 32;
  short8v stk0, stk1, stv0, stv1;

  for (int jt = 0; jt < 32; ++jt) {
    const int j0 = jt * 64;
    const bool have_next = (jt < 31);

    // v(jt) from regs -> LDS (post-B2(jt-1); all PV reads of v(jt-1) done)
    if (jt > 0) {
      *(short8v*)&vt_lds[srow0*64 + ((sc ^ (srow0 & 7))*8)] = stv0;
      *(short8v*)&vt_lds[srow1*64 + ((sc ^ (srow1 & 7))*8)] = stv1;
    }
    if (have_next) {                 // issue next-tile global loads
      const int j0n = j0 + 64;
      stk0 = *(const short8v*)&kb[(size_t)(j0n + srow0)*64 + sc*8];
      stk1 = *(const short8v*)&kb[(size_t)(j0n + srow1)*64 + sc*8];
      stv0 = *(const short8v*)&vtb[(size_t)srow0*2048 + j0n + sc*8];
      stv1 = *(const short8v*)&vtb[(size_t)srow1*2048 + j0n + sc*8];
    }

    // --- QK^T: 2 C-tiles (n=0,1), K=64 in 2 steps ---
    f32x4 c0 = {0,0,0,0}, c1 = {0,0,0,0};
    {
      const int jr0 = jh*32 + lrow, jr1 = jh*32 + 16 + lrow;
      const short8v b00 = *(const short8v*)&k_lds[jr0*64 + ((g*8) ^ swz)];
      const short8v b01 = *(const short8v*)&k_lds[jr0*64 + ((32 + g*8) ^ swz)];
      const short8v b10 = *(const short8v*)&k_lds[jr1*64 + ((g*8) ^ swz)];
      const short8v b11 = *(const short8v*)&k_lds[jr1*64 + ((32 + g*8) ^ swz)];
      c0 = MFMA16x16x32(aq0, b00, c0);
      c0 = MFMA16x16x32(aq1, b01, c0);
      c1 = MFMA16x16x32(aq0, b10, c1);
      c1 = MFMA16x16x32(aq1, b11, c1);
    }

    const float m0v = (1.0f - mb[j0 + jh*32 + lrow])      * -10000.0f;
    const float m1v = (1.0f - mb[j0 + jh*32 + 16 + lrow]) * -10000.0f;

    if (j0 <= i0 - 192) {            // whole tile -> bucket 0
      #pragma unroll
      for (int r = 0; r < 4; ++r) {
        const int il  = ih*16 + 4*g + r;
        const int wsw = ((4*g + r) & 7) << 3;
        const float p0 = __expf(c0[r]*0.125f + rs_lo[r] + m0v - 8.0f);
        const float p1 = __expf(c1[r]*0.125f + rs_lo[r] + m1v - 8.0f);
        qp_lds[il*64 + ((jh*32 + lrow) ^ wsw)]      = f2bf(p0);
        qp_lds[il*64 + ((jh*32 + 16 + lrow) ^ wsw)] = f2bf(p1);
        rpl_p[r] += p0 + p1; ls_p[r] += p0 + p1;
      }
    } else if (j0 >= i0 + 159) {     // whole tile -> bucket 255
      #pragma unroll
      for (int r = 0; r < 4; ++r) {
        const int il  = ih*16 + 4*g + r;
        const int wsw = ((4*g + r) & 7) << 3;
        const float p0 = __expf(c0[r]*0.125f + rs_hi[r] + m0v - 8.0f);
        const float p1 = __expf(c1[r]*0.125f + rs_hi[r] + m1v - 8.0f);
        qp_lds[il*64 + ((jh*32 + lrow) ^ wsw)]      = f2bf(p0);
        qp_lds[il*64 + ((jh*32 + 16 + lrow) ^ wsw)] = f2bf(p1);
        rph_p[r] += p0 + p1; ls_p[r] += p0 + p1;
      }
    } else {                         // band: per-element bucket
      #pragma unroll
      for (int r = 0; r < 4; ++r) {
        const int il  = ih*16 + 4*g + r;
        const int gi  = i0 + il;
        const int wsw = ((4*g + r) & 7) << 3;
        {
          const int jl = jh*32 + lrow, gj = j0 + jl;
          int rel = gj - gi; rel = rel < -128 ? -128 : (rel > 127 ? 127 : rel);
          const int bk = rel + 128;
          const float rsv = bf2f(rs_ldsb[il*256 + (((bk >> 3) ^ (il & 7)) << 3) + (bk & 7)]);
          const float p = __expf(c0[r]*0.125f + rsv + m0v - 8.0f);
          qp_lds[il*64 + (jl ^ wsw)] = f2bf(p);
          if (bk == 0)        rpl_p[r] += p;
          else if (bk == 255) rph_p[r] += p;
          else rp_bf[il*256 + (((bk >> 3) ^ (il & 7)) << 3) + (bk & 7)] = f2bf(p);
          ls_p[r] += p;
        }
        {
          const int jl = jh*32 + 16 + lrow, gj = j0 + jl;
          int rel = gj - gi; rel = rel < -128 ? -128 : (rel > 127 ? 127 : rel);
          const int bk = rel + 128;
          const float rsv = bf2f(rs_ldsb[il*256 + (((bk >> 3) ^ (il & 7)) << 3) + (bk & 7)]);
          const float p = __expf(c1[r]*0.125f + rsv + m1v - 8.0f);
          qp_lds[il*64 + (jl ^ wsw)] = f2bf(p);
          if (bk == 0)        rpl_p[r] += p;
          else if (bk == 255) rph_p[r] += p;
          else rp_bf[il*256 + (((bk >> 3) ^ (il & 7)) << 3) + (bk & 7)] = f2bf(p);
          ls_p[r] += p;
        }
      }
    }
    __syncthreads();                 // B1: p visible; all k(jt) reads done

    // k(jt+1) from regs -> LDS (k(jt) dead)
    if (have_next) {
      *(short8v*)&k_lds[srow0*64 + ((sc ^ (srow0 & 7))*8)] = stk0;
      *(short8v*)&k_lds[srow1*64 + ((sc ^ (srow1 & 7))*8)] = stk1;
    }

    // --- PV: ctx[i][d] += P[i][:] @ V[:, d] ---
    {
      const int prow = ih*16 + lrow;
      const short8v pa0 = *(const short8v*)&qp_lds[prow*64 + ((g*8) ^ swz)];
      const short8v pa1 = *(const short8v*)&qp_lds[prow*64 + ((32 + g*8) ^ swz)];
      const int d0 = jh*32 + lrow, d1 = jh*32 + 16 + lrow;
      const short8v vb00 = *(const short8v*)&vt_lds[d0*64 + ((g*8) ^ swz)];
      const short8v vb01 = *(const short8v*)&vt_lds[d0*64 + ((32 + g*8) ^ swz)];
      const short8v vb10 = *(const short8v*)&vt_lds[d1*64 + ((g*8) ^ swz)];
      const short8v vb11 = *(const short8v*)&vt_lds[d1*64 + ((32 + g*8) ^ swz)];
      ctx0 = MFMA16x16x32(pa0, vb00, ctx0);
      ctx0 = MFMA16x16x32(pa1, vb01, ctx0);
      ctx1 = MFMA16x16x32(pa0, vb10, ctx1);
      ctx1 = MFMA16x16x32(pa1, vb11, ctx1);
    }
    __syncthreads();                 // B2: PV reads done; k(jt+1) visible
  }

  // --- fold per-lane partials (edges + row sums), once ---
  #pragma unroll
  for (int r = 0; r < 4; ++r) {
    float a = ls_p[r], bl = rpl_p[r], bhv = rph_p[r];
    #pragma unroll
    for (int m = 1; m < 16; m <<= 1) {
      a   += __shfl_xor(a, m);
      bl  += __shfl_xor(bl, m);
      bhv += __shfl_xor(bhv, m);
    }
    if (lrow == 0) {
      const int il = ih*16 + 4*g + r;
      LDS_ATOMIC_ADD(&l_s[il], a);
      LDS_ATOMIC_ADD(&edge_f[2*il + 0], bl);
      LDS_ATOMIC_ADD(&edge_f[2*il + 1], bhv);
    }
  }
  __syncthreads();

  // patch rp_bf edge buckets
  if (t < 32) {
    const int row = t;
    rp_bf[row*256 + (((0  ^ (row & 7))) << 3) + 0] = f2bf(edge_f[2*row + 0]);
    rp_bf[row*256 + (((31 ^ (row & 7))) << 3) + 7] = f2bf(edge_f[2*row + 1]);
  }
  __syncthreads();

  // --- rel-value epilogue: ctx += rp @ rve (K=256) ---
  {
    const int arow = ih*16 + lrow;
    const int d0 = jh*32 + lrow, d1 = jh*32 + 16 + lrow;
    #pragma unroll
    for (int ks = 0; ks < 8; ++ks) {
      const short8v a  = *(const short8v*)&rp_bf[arow*256 + (((ks*4 + g) ^ (lrow & 7))*8)];
      const short8v b0 = *(const short8v*)&rvet[d0*256 + ks*32 + g*8];
      const short8v b1 = *(const short8v*)&rvet[d1*256 + ks*32 + g*8];
      ctx0 = MFMA16x16x32(a, b0, ctx0);
      ctx1 = MFMA16x16x32(a, b1, ctx1);
    }
  }

  // --- normalize + store ---
  #pragma unroll
  for (int r = 0; r < 4; ++r) {
    const int il = ih*16 + 4*g + r;
    const float invl = 1.0f / l_s[il];
    const int gi = i0 + il;
    out[(size_t)(b*2048 + gi)*768 + h*64 + jh*32 + lrow]      = ctx0[r] * invl;
    out[(size_t)(b*2048 + gi)*768 + h*64 + jh*32 + 16 + lrow] = ctx1[r] * invl;
  }
}

// ---------------- launcher ----------------
extern "C" void kernel_launch(void* const* d_in, const int* in_sizes, int n_in,
                              void* d_out, int out_size, void* d_ws, size_t ws_size,
                              hipStream_t stream) {
  const float* hs   = (const float*)d_in[0];
  const float* mask = (const float*)d_in[1];
  const float* Wq   = (const float*)d_in[2];
  const float* bq   = (const float*)d_in[3];
  const float* Wk   = (const float*)d_in[4];
  const float* bk   = (const float*)d_in[5];
  const float* Wv   = (const float*)d_in[6];
  const float* bv   = (const float*)d_in[7];
  const float* rke  = (const float*)d_in[8];
  const float* rve  = (const float*)d_in[9];
  // d_in[10] = indices, recomputed analytically on device.

  // Workspace (shorts, all disjoint): wt 1.77M | qbf/kbf/vbf/vtbf 3.1M ea |
  // rvet/rkeb 16K ea = 28.77 MB total.
  const size_t need_bytes = 28770304;
  if (ws_size < need_bytes) return;

  short* p     = (short*)d_ws;
  short* wtb   = p;                       // 1,769,472
  short* qbf   = p + 1769472;             // 3,145,728
  short* kbf   = p + 4915200;
  short* vbf   = p + 8060928;
  short* vtbf  = p + 11206656;
  short* rvet  = p + 14352384;            // 16,384
  short* rkeb  = p + 14368768;            // 16,384
  float* out   = (float*)d_out;

  prep_wt_kernel<<<dim3(12, 12, 3), dim3(256), 0, stream>>>(Wq, Wk, Wv, wtb);
  rvet_kernel<<<dim3(64), dim3(256), 0, stream>>>(rve, rke, rvet, rkeb);
  qkv_mfma_kernel<<<dim3(32, 6, 3), dim3(256), 0, stream>>>(
      hs, wtb, bq, bk, bv, qbf, kbf, vbf);
  transpose_v_kernel<<<dim3(32, 24), dim3(256), 0, stream>>>(vbf, vtbf);
  attn_mfma_kernel<<<dim3(64, 24), dim3(256), 0, stream>>>(
      qbf, kbf, vtbf, rkeb, rvet, mask, out);
}